// Round 3
// baseline (347.909 us; speedup 1.0000x reference)
//
#include <hip/hip_runtime.h>

#define NEG_SLOPE 0.2f

// ---------------- GEMM1: h1 = x @ W1 (128x128) + attention logits ----------------
// 16 nodes per block, 128 threads; thread t owns output channel t.
// h1 written in interleaved pair layout: h1p[n*64+c] = {h[n][c], h[n][c+64]}
__global__ __launch_bounds__(128) void k_gemm1(
    const float* __restrict__ x, const float* __restrict__ W1,
    const float* __restrict__ as1, const float* __restrict__ ad1,
    float2* __restrict__ h1p, float* __restrict__ alsrc, float* __restrict__ aldst,
    int N) {
    __shared__ float xs[16][128];
    __shared__ float tr[2][128];
    int t = threadIdx.x;
    int n0 = blockIdx.x * 16;
#pragma unroll
    for (int j = 0; j < 16; j++) {
        int n = n0 + j;
        xs[j][t] = (n < N) ? x[(size_t)n * 128 + t] : 0.f;
    }
    __syncthreads();
    float acc[16];
#pragma unroll
    for (int j = 0; j < 16; j++) acc[j] = 0.f;
    for (int k = 0; k < 128; k++) {
        float w = W1[k * 128 + t];
#pragma unroll
        for (int j = 0; j < 16; j++) acc[j] = fmaf(xs[j][k], w, acc[j]);
    }
    int h = t >> 6, c = t & 63;
    float asv = as1[t];
    float adv = ad1[t];
#pragma unroll
    for (int j = 0; j < 16; j++) {
        int n = n0 + j;
        float vs = acc[j] * asv, vd = acc[j] * adv;
#pragma unroll
        for (int o = 32; o > 0; o >>= 1) {
            vs += __shfl_down(vs, o);
            vd += __shfl_down(vd, o);
        }
        if (c == 0 && n < N) {
            alsrc[n * 2 + h] = vs;
            aldst[n * 2 + h] = vd;
        }
    }
    // transpose-write h1 pairs: 2 nodes per round (one per wave)
    for (int j = 0; j < 16; j += 2) {
        tr[h][t & 127 ? t : t] = 0.f;  // no-op placeholder removed below
        __syncthreads();
        tr[0][t] = acc[j];
        tr[1][t] = acc[j + 1];
        __syncthreads();
        int n = n0 + j + h;
        if (n < N) {
            float2 p = make_float2(tr[h][c], tr[h][c + 64]);
            h1p[(size_t)n * 64 + c] = p;
        }
        __syncthreads();
    }
}

// ---------------- GEMM2: h2 = hf @ W2 (128x40) + attention logits ----------------
__global__ __launch_bounds__(256) void k_gemm2(
    const float* __restrict__ hf, const float* __restrict__ W2,
    const float* __restrict__ as2, const float* __restrict__ ad2,
    float* __restrict__ h2, float* __restrict__ alsrc, float* __restrict__ aldst,
    int N) {
    __shared__ float xs[4][128];
    int wave = threadIdx.x >> 6, lane = threadIdx.x & 63;
    int n = blockIdx.x * 4 + wave;
    if (n < N) {
        xs[wave][lane] = hf[(size_t)n * 128 + lane];
        xs[wave][lane + 64] = hf[(size_t)n * 128 + lane + 64];
    }
    __syncthreads();
    float acc = 0.f;
    if (n < N && lane < 40) {
#pragma unroll 16
        for (int k = 0; k < 128; k++) acc = fmaf(xs[wave][k], W2[k * 40 + lane], acc);
        h2[(size_t)n * 40 + lane] = acc;
    }
    float vs = (n < N && lane < 40) ? acc * as2[lane] : 0.f;
    float vd = (n < N && lane < 40) ? acc * ad2[lane] : 0.f;
#pragma unroll
    for (int o = 32; o > 0; o >>= 1) {
        vs += __shfl_down(vs, o);
        vd += __shfl_down(vd, o);
    }
    if (lane == 0 && n < N) {
        alsrc[n] = vs;
        aldst[n] = vd;
    }
}

// ---------------- CSR build ----------------
__global__ void k_count(const int* __restrict__ ei, int* __restrict__ cnt, int E, int ET) {
    int e = blockIdx.x * blockDim.x + threadIdx.x;
    if (e >= ET) return;
    int d = (e < E) ? ei[E + e] : e - E;
    atomicAdd(&cnt[d], 1);
}

__global__ __launch_bounds__(256) void k_scan1(const int* __restrict__ cnt,
                                               int* __restrict__ loc,
                                               int* __restrict__ sums, int N) {
    __shared__ int sh[256];
    int i = blockIdx.x * 256 + threadIdx.x;
    int v = (i < N) ? cnt[i] : 0;
    sh[threadIdx.x] = v;
    __syncthreads();
    for (int o = 1; o < 256; o <<= 1) {
        int t = (threadIdx.x >= o) ? sh[threadIdx.x - o] : 0;
        __syncthreads();
        sh[threadIdx.x] += t;
        __syncthreads();
    }
    if (i < N) loc[i] = sh[threadIdx.x];
    if (threadIdx.x == 255) sums[blockIdx.x] = sh[255];
}

__global__ __launch_bounds__(256) void k_scan2(int* __restrict__ sums, int nb) {
    __shared__ int sh[256];
    int v = (threadIdx.x < nb) ? sums[threadIdx.x] : 0;
    sh[threadIdx.x] = v;
    __syncthreads();
    for (int o = 1; o < 256; o <<= 1) {
        int t = (threadIdx.x >= o) ? sh[threadIdx.x - o] : 0;
        __syncthreads();
        sh[threadIdx.x] += t;
        __syncthreads();
    }
    if (threadIdx.x < nb) sums[threadIdx.x] = sh[threadIdx.x] - v;  // exclusive
}

__global__ __launch_bounds__(256) void k_scan3(const int* __restrict__ cnt,
                                               const int* __restrict__ loc,
                                               const int* __restrict__ sums,
                                               int* __restrict__ rowptr,
                                               int* __restrict__ woff, int N, int ET) {
    int i = blockIdx.x * 256 + threadIdx.x;
    if (i == 0) rowptr[N] = ET;
    if (i >= N) return;
    int v = sums[blockIdx.x] + loc[i] - cnt[i];
    rowptr[i] = v;
    woff[i] = v;
}

__global__ void k_scatter(const int* __restrict__ ei, int* __restrict__ woff,
                          int* __restrict__ col, int E, int ET) {
    int e = blockIdx.x * blockDim.x + threadIdx.x;
    if (e >= ET) return;
    int s = (e < E) ? ei[e] : e - E;
    int d = (e < E) ? ei[E + e] : e - E;
    int pos = atomicAdd(&woff[d], 1);
    col[pos] = s;
}

// ---------------- fused gather layer 1 ----------------
// one wave per dst node; lane owns channel pair {lane, lane+64}
__global__ __launch_bounds__(256) void k_gather1(
    const int* __restrict__ rowptr, const int* __restrict__ col,
    const float2* __restrict__ h1p, const float2* __restrict__ alsrc,
    const float2* __restrict__ aldst, const float* __restrict__ b1,
    float* __restrict__ hf, int N) {
    int wid = (int)(((size_t)blockIdx.x * blockDim.x + threadIdx.x) >> 6);
    int lane = threadIdx.x & 63;
    if (wid >= N) return;
    int start = rowptr[wid], end = rowptr[wid + 1];
    float2 ad = aldst[wid];
    float m0 = -1e30f, m1 = -1e30f, s0 = 0.f, s1 = 0.f, a0 = 0.f, a1 = 0.f;
    for (int base = start; base < end; base += 64) {
        int nb = min(64, end - base);
        int sv = 0;
        float l0 = -1e30f, l1 = -1e30f;
        if (lane < nb) {
            sv = col[base + lane];
            float2 asv = alsrc[sv];
            float t0 = asv.x + ad.x, t1 = asv.y + ad.y;
            l0 = (t0 > 0.f) ? t0 : NEG_SLOPE * t0;
            l1 = (t1 > 0.f) ? t1 : NEG_SLOPE * t1;
        }
        // chunk max (wave reduce)
        float c0 = l0, c1 = l1;
#pragma unroll
        for (int o = 32; o > 0; o >>= 1) {
            c0 = fmaxf(c0, __shfl_xor(c0, o));
            c1 = fmaxf(c1, __shfl_xor(c1, o));
        }
        // merge with running max; rescale once per chunk
        if (c0 > m0) { float sc = __expf(m0 - c0); s0 *= sc; a0 *= sc; m0 = c0; }
        if (c1 > m1) { float sc = __expf(m1 - c1); s1 *= sc; a1 *= sc; m1 = c1; }
        // lane-parallel exp + denominator reduce
        float e0 = (lane < nb) ? __expf(l0 - m0) : 0.f;
        float e1 = (lane < nb) ? __expf(l1 - m1) : 0.f;
        float t0 = e0, t1 = e1;
#pragma unroll
        for (int o = 32; o > 0; o >>= 1) {
            t0 += __shfl_xor(t0, o);
            t1 += __shfl_xor(t1, o);
        }
        s0 += t0; s1 += t1;
        // gather + weighted accumulate
        for (int j = 0; j < nb; j++) {
            int s = __shfl(sv, j);
            float w0 = __shfl(e0, j), w1 = __shfl(e1, j);
            float2 hv = h1p[(size_t)s * 64 + lane];
            a0 = fmaf(w0, hv.x, a0);
            a1 = fmaf(w1, hv.y, a1);
        }
    }
    float v0 = a0 / (s0 + 1e-16f) + b1[lane];
    float v1 = a1 / (s1 + 1e-16f) + b1[64 + lane];
    hf[(size_t)wid * 128 + lane] = (v0 > 0.f) ? v0 : expm1f(v0);
    hf[(size_t)wid * 128 + 64 + lane] = (v1 > 0.f) ? v1 : expm1f(v1);
}

// ---------------- fused gather layer 2 ----------------
__global__ __launch_bounds__(256) void k_gather2(
    const int* __restrict__ rowptr, const int* __restrict__ col,
    const float* __restrict__ h2, const float* __restrict__ alsrc,
    const float* __restrict__ aldst, const float* __restrict__ b2,
    float* __restrict__ out, int N) {
    int wid = (int)(((size_t)blockIdx.x * blockDim.x + threadIdx.x) >> 6);
    int lane = threadIdx.x & 63;
    if (wid >= N) return;
    int start = rowptr[wid], end = rowptr[wid + 1];
    float ad = aldst[wid];
    float m = -1e30f, s = 0.f, a = 0.f;
    for (int base = start; base < end; base += 64) {
        int nb = min(64, end - base);
        int sv = 0;
        float l = -1e30f;
        if (lane < nb) {
            sv = col[base + lane];
            float t = alsrc[sv] + ad;
            l = (t > 0.f) ? t : NEG_SLOPE * t;
        }
        float c = l;
#pragma unroll
        for (int o = 32; o > 0; o >>= 1) c = fmaxf(c, __shfl_xor(c, o));
        if (c > m) { float sc = __expf(m - c); s *= sc; a *= sc; m = c; }
        float e = (lane < nb) ? __expf(l - m) : 0.f;
        float t = e;
#pragma unroll
        for (int o = 32; o > 0; o >>= 1) t += __shfl_xor(t, o);
        s += t;
        for (int j = 0; j < nb; j++) {
            int src = __shfl(sv, j);
            float w = __shfl(e, j);
            if (lane < 40) {
                float hv = h2[(size_t)src * 40 + lane];
                a = fmaf(w, hv, a);
            }
        }
    }
    if (lane < 40) out[(size_t)wid * 40 + lane] = a / (s + 1e-16f) + b2[lane];
}

extern "C" void kernel_launch(void* const* d_in, const int* in_sizes, int n_in,
                              void* d_out, int out_size, void* d_ws, size_t ws_size,
                              hipStream_t stream) {
    const float* x   = (const float*)d_in[0];
    const int*   ei  = (const int*)d_in[1];
    const float* W1  = (const float*)d_in[2];
    const float* as1 = (const float*)d_in[3];
    const float* ad1 = (const float*)d_in[4];
    const float* b1  = (const float*)d_in[5];
    const float* W2  = (const float*)d_in[6];
    const float* as2 = (const float*)d_in[7];
    const float* ad2 = (const float*)d_in[8];
    const float* b2  = (const float*)d_in[9];
    int N = in_sizes[0] / 128;
    int E = in_sizes[1] / 2;
    int ET = E + N;
    float* out = (float*)d_out;

    char* ws = (char*)d_ws;
    size_t off = 0;
    auto alloc = [&](size_t bytes) {
        char* p = ws + off;
        off += (bytes + 255) & ~(size_t)255;
        return p;
    };
    int nb = (N + 255) / 256;
    int*   cnt    = (int*)alloc((size_t)N * 4);  // zero-init
    int*   loc    = (int*)alloc((size_t)N * 4);
    int*   sums   = (int*)alloc(256 * 4);
    int*   rowptr = (int*)alloc(((size_t)N + 1) * 4);
    int*   woff   = (int*)alloc((size_t)N * 4);
    int*   colbuf = (int*)alloc((size_t)ET * 4);
    float2* h1p   = (float2*)alloc((size_t)N * 64 * 8);
    float* hf     = (float*)alloc((size_t)N * 128 * 4);
    float* h2     = (float*)alloc((size_t)N * 40 * 4);
    float* alsrc1 = (float*)alloc((size_t)N * 2 * 4);
    float* aldst1 = (float*)alloc((size_t)N * 2 * 4);
    float* alsrc2 = (float*)alloc((size_t)N * 4);
    float* aldst2 = (float*)alloc((size_t)N * 4);

    hipMemsetAsync(cnt, 0, (size_t)N * 4, stream);

    dim3 b256(256);
    int gE = (ET + 255) / 256;

    // CSR build (shared by both layers)
    k_count<<<gE, b256, 0, stream>>>(ei, cnt, E, ET);
    k_scan1<<<nb, b256, 0, stream>>>(cnt, loc, sums, N);
    k_scan2<<<1, b256, 0, stream>>>(sums, nb);
    k_scan3<<<nb, b256, 0, stream>>>(cnt, loc, sums, rowptr, woff, N, ET);
    k_scatter<<<gE, b256, 0, stream>>>(ei, woff, colbuf, E, ET);

    // layer 1
    k_gemm1<<<dim3((N + 15) / 16), dim3(128), 0, stream>>>(x, W1, as1, ad1, h1p, alsrc1, aldst1, N);
    k_gather1<<<(int)(((size_t)N * 64 + 255) / 256), b256, 0, stream>>>(
        rowptr, colbuf, h1p, (const float2*)alsrc1, (const float2*)aldst1, b1, hf, N);

    // layer 2
    k_gemm2<<<(N + 3) / 4, b256, 0, stream>>>(hf, W2, as2, ad2, h2, alsrc2, aldst2, N);
    k_gather2<<<(int)(((size_t)N * 64 + 255) / 256), b256, 0, stream>>>(
        rowptr, colbuf, h2, alsrc2, aldst2, b2, out, N);
}

// Round 4
// 286.782 us; speedup vs baseline: 1.2131x; 1.2131x over previous
//
#include <hip/hip_runtime.h>
#include <hip/hip_fp16.h>

#define NEG_SLOPE 0.2f

// ---------------- GEMM1: h1 = x @ W1 (128x128) + attention logits ----------------
// 16 nodes per block, 128 threads; thread t owns output channel t.
// h1 stored fp16 pair layout: h1h[n*64+c] = half2{h[n][2c], h[n][2c+1]}
__global__ __launch_bounds__(128) void k_gemm1(
    const float* __restrict__ x, const float* __restrict__ W1,
    const float* __restrict__ as1, const float* __restrict__ ad1,
    __half2* __restrict__ h1h, float* __restrict__ alsrc, float* __restrict__ aldst,
    int N) {
    __shared__ float xs[16][128];
    int t = threadIdx.x;
    int n0 = blockIdx.x * 16;
#pragma unroll
    for (int j = 0; j < 16; j++) {
        int n = n0 + j;
        xs[j][t] = (n < N) ? x[(size_t)n * 128 + t] : 0.f;
    }
    __syncthreads();
    float acc[16];
#pragma unroll
    for (int j = 0; j < 16; j++) acc[j] = 0.f;
    for (int k = 0; k < 128; k++) {
        float w = W1[k * 128 + t];
#pragma unroll
        for (int j = 0; j < 16; j++) acc[j] = fmaf(xs[j][k], w, acc[j]);
    }
    int h = t >> 6, c = t & 63;
    float asv = as1[t];
    float adv = ad1[t];
#pragma unroll
    for (int j = 0; j < 16; j++) {
        int n = n0 + j;
        float vs = acc[j] * asv, vd = acc[j] * adv;
#pragma unroll
        for (int o = 32; o > 0; o >>= 1) {
            vs += __shfl_down(vs, o);
            vd += __shfl_down(vd, o);
        }
        if (c == 0 && n < N) {
            alsrc[n * 2 + h] = vs;
            aldst[n * 2 + h] = vd;
        }
        // pair write: even thread t packs channels {t, t+1}
        float part = __shfl_down(acc[j], 1);
        if (((t & 1) == 0) && n < N)
            h1h[(size_t)n * 64 + (t >> 1)] = __floats2half2_rn(acc[j], part);
    }
}

// ---------------- GEMM2: h2 = hf @ W2 (128x40) + attention logits ----------------
// h2 stored fp16 pair layout: h2h[n*20+c] = half2{h2[n][2c], h2[n][2c+1]}
__global__ __launch_bounds__(256) void k_gemm2(
    const float* __restrict__ hf, const float* __restrict__ W2,
    const float* __restrict__ as2, const float* __restrict__ ad2,
    __half2* __restrict__ h2h, float* __restrict__ alsrc, float* __restrict__ aldst,
    int N) {
    __shared__ float xs[4][128];
    int wave = threadIdx.x >> 6, lane = threadIdx.x & 63;
    int n = blockIdx.x * 4 + wave;
    if (n < N) {
        xs[wave][lane] = hf[(size_t)n * 128 + lane];
        xs[wave][lane + 64] = hf[(size_t)n * 128 + lane + 64];
    }
    __syncthreads();
    float acc = 0.f;
    if (n < N && lane < 40) {
#pragma unroll 16
        for (int k = 0; k < 128; k++) acc = fmaf(xs[wave][k], W2[k * 40 + lane], acc);
    }
    float part = __shfl_down(acc, 1);
    if (n < N && lane < 40 && ((lane & 1) == 0))
        h2h[(size_t)n * 20 + (lane >> 1)] = __floats2half2_rn(acc, part);
    float vs = (n < N && lane < 40) ? acc * as2[lane] : 0.f;
    float vd = (n < N && lane < 40) ? acc * ad2[lane] : 0.f;
#pragma unroll
    for (int o = 32; o > 0; o >>= 1) {
        vs += __shfl_down(vs, o);
        vd += __shfl_down(vd, o);
    }
    if (lane == 0 && n < N) {
        alsrc[n] = vs;
        aldst[n] = vd;
    }
}

// ---------------- CSR build ----------------
__global__ void k_count(const int* __restrict__ ei, int* __restrict__ cnt, int E, int ET) {
    int e = blockIdx.x * blockDim.x + threadIdx.x;
    if (e >= ET) return;
    int d = (e < E) ? ei[E + e] : e - E;
    atomicAdd(&cnt[d], 1);
}

__global__ __launch_bounds__(256) void k_scan1(const int* __restrict__ cnt,
                                               int* __restrict__ loc,
                                               int* __restrict__ sums, int N) {
    __shared__ int sh[256];
    int i = blockIdx.x * 256 + threadIdx.x;
    int v = (i < N) ? cnt[i] : 0;
    sh[threadIdx.x] = v;
    __syncthreads();
    for (int o = 1; o < 256; o <<= 1) {
        int t = (threadIdx.x >= o) ? sh[threadIdx.x - o] : 0;
        __syncthreads();
        sh[threadIdx.x] += t;
        __syncthreads();
    }
    if (i < N) loc[i] = sh[threadIdx.x];
    if (threadIdx.x == 255) sums[blockIdx.x] = sh[255];
}

__global__ __launch_bounds__(256) void k_scan2(int* __restrict__ sums, int nb) {
    __shared__ int sh[256];
    int v = (threadIdx.x < nb) ? sums[threadIdx.x] : 0;
    sh[threadIdx.x] = v;
    __syncthreads();
    for (int o = 1; o < 256; o <<= 1) {
        int t = (threadIdx.x >= o) ? sh[threadIdx.x - o] : 0;
        __syncthreads();
        sh[threadIdx.x] += t;
        __syncthreads();
    }
    if (threadIdx.x < nb) sums[threadIdx.x] = sh[threadIdx.x] - v;  // exclusive
}

__global__ __launch_bounds__(256) void k_scan3(const int* __restrict__ cnt,
                                               const int* __restrict__ loc,
                                               const int* __restrict__ sums,
                                               int* __restrict__ rowptr,
                                               int* __restrict__ woff, int N, int ET) {
    int i = blockIdx.x * 256 + threadIdx.x;
    if (i == 0) rowptr[N] = ET;
    if (i >= N) return;
    int v = sums[blockIdx.x] + loc[i] - cnt[i];
    rowptr[i] = v;
    woff[i] = v;
}

__global__ void k_scatter(const int* __restrict__ ei, int* __restrict__ woff,
                          int* __restrict__ col, int E, int ET) {
    int e = blockIdx.x * blockDim.x + threadIdx.x;
    if (e >= ET) return;
    int s = (e < E) ? ei[e] : e - E;
    int d = (e < E) ? ei[E + e] : e - E;
    int pos = atomicAdd(&woff[d], 1);
    col[pos] = s;
}

// ---------------- fused gather layer 1 ----------------
// one wave per dst node; lane c owns channels {2c, 2c+1}; head = (c<32) ? 0 : 1
__global__ __launch_bounds__(256) void k_gather1(
    const int* __restrict__ rowptr, const int* __restrict__ col,
    const __half2* __restrict__ h1h, const float2* __restrict__ alsrc,
    const float2* __restrict__ aldst, const float* __restrict__ b1,
    float2* __restrict__ hf2, int N) {
    int wid = (int)(((size_t)blockIdx.x * blockDim.x + threadIdx.x) >> 6);
    int lane = threadIdx.x & 63;
    if (wid >= N) return;
    int start = rowptr[wid], end = rowptr[wid + 1];
    float2 ad = aldst[wid];
    bool hl = lane < 32;
    float m0 = -1e30f, m1 = -1e30f, s0 = 0.f, s1 = 0.f, a0 = 0.f, a1 = 0.f;
    for (int base = start; base < end; base += 64) {
        int nb = min(64, end - base);
        int sv = 0;
        float l0 = -1e30f, l1 = -1e30f;
        if (lane < nb) {
            sv = col[base + lane];
            float2 asv = alsrc[sv];
            float t0 = asv.x + ad.x, t1 = asv.y + ad.y;
            l0 = (t0 > 0.f) ? t0 : NEG_SLOPE * t0;
            l1 = (t1 > 0.f) ? t1 : NEG_SLOPE * t1;
        }
        float c0 = l0, c1 = l1;
#pragma unroll
        for (int o = 32; o > 0; o >>= 1) {
            c0 = fmaxf(c0, __shfl_xor(c0, o));
            c1 = fmaxf(c1, __shfl_xor(c1, o));
        }
        float sc0 = 1.f, sc1 = 1.f;
        if (c0 > m0) { sc0 = __expf(m0 - c0); s0 *= sc0; m0 = c0; }
        if (c1 > m1) { sc1 = __expf(m1 - c1); s1 *= sc1; m1 = c1; }
        float msc = hl ? sc0 : sc1;
        a0 *= msc; a1 *= msc;
        float e0 = (lane < nb) ? __expf(l0 - m0) : 0.f;
        float e1 = (lane < nb) ? __expf(l1 - m1) : 0.f;
        float t0 = e0, t1 = e1;
#pragma unroll
        for (int o = 32; o > 0; o >>= 1) {
            t0 += __shfl_xor(t0, o);
            t1 += __shfl_xor(t1, o);
        }
        s0 += t0; s1 += t1;
        // gather: 4-deep load pipeline
        int j = 0;
        for (; j + 4 <= nb; j += 4) {
            int sA = __shfl(sv, j),     sB = __shfl(sv, j + 1),
                sC = __shfl(sv, j + 2), sD = __shfl(sv, j + 3);
            __half2 vA = h1h[(size_t)sA * 64 + lane];
            __half2 vB = h1h[(size_t)sB * 64 + lane];
            __half2 vC = h1h[(size_t)sC * 64 + lane];
            __half2 vD = h1h[(size_t)sD * 64 + lane];
            float wA0 = __shfl(e0, j),     wA1 = __shfl(e1, j);
            float wB0 = __shfl(e0, j + 1), wB1 = __shfl(e1, j + 1);
            float wC0 = __shfl(e0, j + 2), wC1 = __shfl(e1, j + 2);
            float wD0 = __shfl(e0, j + 3), wD1 = __shfl(e1, j + 3);
            float wA = hl ? wA0 : wA1, wB = hl ? wB0 : wB1;
            float wC = hl ? wC0 : wC1, wD = hl ? wD0 : wD1;
            float2 fA = __half22float2(vA), fB = __half22float2(vB);
            float2 fC = __half22float2(vC), fD = __half22float2(vD);
            a0 = fmaf(wA, fA.x, a0); a1 = fmaf(wA, fA.y, a1);
            a0 = fmaf(wB, fB.x, a0); a1 = fmaf(wB, fB.y, a1);
            a0 = fmaf(wC, fC.x, a0); a1 = fmaf(wC, fC.y, a1);
            a0 = fmaf(wD, fD.x, a0); a1 = fmaf(wD, fD.y, a1);
        }
        for (; j < nb; j++) {
            int s = __shfl(sv, j);
            float w0 = __shfl(e0, j), w1 = __shfl(e1, j);
            float w = hl ? w0 : w1;
            float2 f = __half22float2(h1h[(size_t)s * 64 + lane]);
            a0 = fmaf(w, f.x, a0);
            a1 = fmaf(w, f.y, a1);
        }
    }
    float denom = (hl ? s0 : s1) + 1e-16f;
    float v0 = a0 / denom + b1[2 * lane];
    float v1 = a1 / denom + b1[2 * lane + 1];
    v0 = (v0 > 0.f) ? v0 : expm1f(v0);
    v1 = (v1 > 0.f) ? v1 : expm1f(v1);
    hf2[(size_t)wid * 64 + lane] = make_float2(v0, v1);
}

// ---------------- fused gather layer 2 ----------------
// lane c (<20) owns channels {2c, 2c+1}
__global__ __launch_bounds__(256) void k_gather2(
    const int* __restrict__ rowptr, const int* __restrict__ col,
    const __half2* __restrict__ h2h, const float* __restrict__ alsrc,
    const float* __restrict__ aldst, const float* __restrict__ b2,
    float2* __restrict__ out2, int N) {
    int wid = (int)(((size_t)blockIdx.x * blockDim.x + threadIdx.x) >> 6);
    int lane = threadIdx.x & 63;
    if (wid >= N) return;
    int start = rowptr[wid], end = rowptr[wid + 1];
    float ad = aldst[wid];
    int ln = (lane < 20) ? lane : 0;  // clamp address; lanes >=20 compute junk, never written
    float m = -1e30f, s = 0.f, a0 = 0.f, a1 = 0.f;
    for (int base = start; base < end; base += 64) {
        int nb = min(64, end - base);
        int sv = 0;
        float l = -1e30f;
        if (lane < nb) {
            sv = col[base + lane];
            float t = alsrc[sv] + ad;
            l = (t > 0.f) ? t : NEG_SLOPE * t;
        }
        float c = l;
#pragma unroll
        for (int o = 32; o > 0; o >>= 1) c = fmaxf(c, __shfl_xor(c, o));
        if (c > m) { float sc = __expf(m - c); s *= sc; a0 *= sc; a1 *= sc; m = c; }
        float e = (lane < nb) ? __expf(l - m) : 0.f;
        float t = e;
#pragma unroll
        for (int o = 32; o > 0; o >>= 1) t += __shfl_xor(t, o);
        s += t;
        int j = 0;
        for (; j + 4 <= nb; j += 4) {
            int sA = __shfl(sv, j),     sB = __shfl(sv, j + 1),
                sC = __shfl(sv, j + 2), sD = __shfl(sv, j + 3);
            __half2 vA = h2h[(size_t)sA * 20 + ln];
            __half2 vB = h2h[(size_t)sB * 20 + ln];
            __half2 vC = h2h[(size_t)sC * 20 + ln];
            __half2 vD = h2h[(size_t)sD * 20 + ln];
            float wA = __shfl(e, j),     wB = __shfl(e, j + 1);
            float wC = __shfl(e, j + 2), wD = __shfl(e, j + 3);
            float2 fA = __half22float2(vA), fB = __half22float2(vB);
            float2 fC = __half22float2(vC), fD = __half22float2(vD);
            a0 = fmaf(wA, fA.x, a0); a1 = fmaf(wA, fA.y, a1);
            a0 = fmaf(wB, fB.x, a0); a1 = fmaf(wB, fB.y, a1);
            a0 = fmaf(wC, fC.x, a0); a1 = fmaf(wC, fC.y, a1);
            a0 = fmaf(wD, fD.x, a0); a1 = fmaf(wD, fD.y, a1);
        }
        for (; j < nb; j++) {
            int src = __shfl(sv, j);
            float w = __shfl(e, j);
            float2 f = __half22float2(h2h[(size_t)src * 20 + ln]);
            a0 = fmaf(w, f.x, a0);
            a1 = fmaf(w, f.y, a1);
        }
    }
    if (lane < 20) {
        float denom = s + 1e-16f;
        out2[(size_t)wid * 20 + lane] =
            make_float2(a0 / denom + b2[2 * lane], a1 / denom + b2[2 * lane + 1]);
    }
}

extern "C" void kernel_launch(void* const* d_in, const int* in_sizes, int n_in,
                              void* d_out, int out_size, void* d_ws, size_t ws_size,
                              hipStream_t stream) {
    const float* x   = (const float*)d_in[0];
    const int*   ei  = (const int*)d_in[1];
    const float* W1  = (const float*)d_in[2];
    const float* as1 = (const float*)d_in[3];
    const float* ad1 = (const float*)d_in[4];
    const float* b1  = (const float*)d_in[5];
    const float* W2  = (const float*)d_in[6];
    const float* as2 = (const float*)d_in[7];
    const float* ad2 = (const float*)d_in[8];
    const float* b2  = (const float*)d_in[9];
    int N = in_sizes[0] / 128;
    int E = in_sizes[1] / 2;
    int ET = E + N;
    float2* out2 = (float2*)d_out;

    char* ws = (char*)d_ws;
    size_t off = 0;
    auto alloc = [&](size_t bytes) {
        char* p = ws + off;
        off += (bytes + 255) & ~(size_t)255;
        return p;
    };
    int nb = (N + 255) / 256;
    int*     cnt    = (int*)alloc((size_t)N * 4);  // zero-init
    int*     loc    = (int*)alloc((size_t)N * 4);
    int*     sums   = (int*)alloc(256 * 4);
    int*     rowptr = (int*)alloc(((size_t)N + 1) * 4);
    int*     woff   = (int*)alloc((size_t)N * 4);
    int*     colbuf = (int*)alloc((size_t)ET * 4);
    __half2* h1h    = (__half2*)alloc((size_t)N * 64 * 4);
    float*   hf     = (float*)alloc((size_t)N * 128 * 4);
    __half2* h2h    = (__half2*)alloc((size_t)N * 20 * 4);
    float*   alsrc1 = (float*)alloc((size_t)N * 2 * 4);
    float*   aldst1 = (float*)alloc((size_t)N * 2 * 4);
    float*   alsrc2 = (float*)alloc((size_t)N * 4);
    float*   aldst2 = (float*)alloc((size_t)N * 4);

    hipMemsetAsync(cnt, 0, (size_t)N * 4, stream);

    dim3 b256(256);
    int gE = (ET + 255) / 256;

    // CSR build (shared by both layers)
    k_count<<<gE, b256, 0, stream>>>(ei, cnt, E, ET);
    k_scan1<<<nb, b256, 0, stream>>>(cnt, loc, sums, N);
    k_scan2<<<1, b256, 0, stream>>>(sums, nb);
    k_scan3<<<nb, b256, 0, stream>>>(cnt, loc, sums, rowptr, woff, N, ET);
    k_scatter<<<gE, b256, 0, stream>>>(ei, woff, colbuf, E, ET);

    // layer 1
    k_gemm1<<<dim3((N + 15) / 16), dim3(128), 0, stream>>>(x, W1, as1, ad1, h1h, alsrc1, aldst1, N);
    k_gather1<<<(int)(((size_t)N * 64 + 255) / 256), b256, 0, stream>>>(
        rowptr, colbuf, h1h, (const float2*)alsrc1, (const float2*)aldst1, b1, (float2*)hf, N);

    // layer 2
    k_gemm2<<<(N + 3) / 4, b256, 0, stream>>>(hf, W2, as2, ad2, h2h, alsrc2, aldst2, N);
    k_gather2<<<(int)(((size_t)N * 64 + 255) / 256), b256, 0, stream>>>(
        rowptr, colbuf, h2h, alsrc2, aldst2, b2, out2, N);
}

// Round 5
// 210.333 us; speedup vs baseline: 1.6541x; 1.3635x over previous
//
#include <hip/hip_runtime.h>
#include <hip/hip_fp16.h>

#define NEG_SLOPE 0.2f

typedef _Float16 f16x8 __attribute__((ext_vector_type(8)));
typedef float f32x4 __attribute__((ext_vector_type(4)));

// ---------------- pack W1/W2 into MFMA B-fragment order (fp16) ----------------
// layout: bp[((ks*NT+nt)*64 + lane)*8 + j] = W[k][col], k=ks*32+(lane>>4)*8+j, col=nt*16+(lane&15)
__global__ __launch_bounds__(256) void k_pack(const float* __restrict__ W1,
                                              const float* __restrict__ W2,
                                              _Float16* __restrict__ bp1,
                                              _Float16* __restrict__ bp2) {
    int idx = blockIdx.x * 256 + threadIdx.x;
    if (idx < 16384) {  // W1: 4 ks * 8 nt * 64 * 8
        int j = idx & 7, l = (idx >> 3) & 63, nt = (idx >> 9) & 7, ks = idx >> 12;
        int k = ks * 32 + (l >> 4) * 8 + j;
        int col = nt * 16 + (l & 15);
        bp1[idx] = (_Float16)W1[k * 128 + col];
    }
    int idx2 = idx - 16384;
    if (idx2 >= 0 && idx2 < 6144) {  // W2: 4 ks * 3 nt * 64 * 8 (cols >=40 zero-padded)
        int j = idx2 & 7, l = (idx2 >> 3) & 63, q = idx2 >> 9;
        int nt = q % 3, ks = q / 3;
        int k = ks * 32 + (l >> 4) * 8 + j;
        int col = nt * 16 + (l & 15);
        bp2[idx2] = (col < 40) ? (_Float16)W2[k * 40 + col] : (_Float16)0.f;
    }
}

// ---------------- GEMM1 (MFMA): h1 = x @ W1 + attention logits ----------------
// 4 waves * 16 nodes = 64 nodes/block. h1 stored fp16 pairs h1h[n*64+c2]={h[2c2],h[2c2+1]}
__global__ __launch_bounds__(256) void k_gemm1(
    const float* __restrict__ x, const _Float16* __restrict__ bp1,
    const float* __restrict__ as1, const float* __restrict__ ad1,
    __half2* __restrict__ h1h, float* __restrict__ alsrc, float* __restrict__ aldst,
    int N) {
    int w = threadIdx.x >> 6, l = threadIdx.x & 63;
    int n0 = blockIdx.x * 64 + w * 16;
    int li = l & 15, lg = l >> 4;
    int arow = n0 + li;
    // A fragments: lane holds x[arow][ks*32 + lg*8 .. +7] as fp16
    f16x8 a[4];
#pragma unroll
    for (int ks = 0; ks < 4; ks++) {
        float4 p0 = make_float4(0, 0, 0, 0), p1 = make_float4(0, 0, 0, 0);
        if (arow < N) {
            const float4* src = (const float4*)(x + (size_t)arow * 128 + ks * 32 + lg * 8);
            p0 = src[0];
            p1 = src[1];
        }
        f16x8 t;
        t[0] = (_Float16)p0.x; t[1] = (_Float16)p0.y; t[2] = (_Float16)p0.z; t[3] = (_Float16)p0.w;
        t[4] = (_Float16)p1.x; t[5] = (_Float16)p1.y; t[6] = (_Float16)p1.z; t[7] = (_Float16)p1.w;
        a[ks] = t;
    }
    f32x4 acc[8];
#pragma unroll
    for (int nt = 0; nt < 8; nt++) acc[nt] = (f32x4){0.f, 0.f, 0.f, 0.f};
    const f16x8* bp = (const f16x8*)bp1;
#pragma unroll
    for (int nt = 0; nt < 8; nt++)
#pragma unroll
        for (int ks = 0; ks < 4; ks++)
            acc[nt] = __builtin_amdgcn_mfma_f32_16x16x32_f16(a[ks], bp[(ks * 8 + nt) * 64 + l],
                                                             acc[nt], 0, 0, 0);
    // D layout: node = n0 + lg*4 + r, col = nt*16 + li
    // attention logit dots (head0 = nt 0..3, head1 = nt 4..7)
    float as1v[8], ad1v[8];
#pragma unroll
    for (int nt = 0; nt < 8; nt++) {
        as1v[nt] = as1[nt * 16 + li];
        ad1v[nt] = ad1[nt * 16 + li];
    }
#pragma unroll
    for (int r = 0; r < 4; r++) {
        float ps0 = 0, ps1 = 0, pd0 = 0, pd1 = 0;
#pragma unroll
        for (int nt = 0; nt < 4; nt++) {
            ps0 = fmaf(acc[nt][r], as1v[nt], ps0);
            pd0 = fmaf(acc[nt][r], ad1v[nt], pd0);
        }
#pragma unroll
        for (int nt = 4; nt < 8; nt++) {
            ps1 = fmaf(acc[nt][r], as1v[nt], ps1);
            pd1 = fmaf(acc[nt][r], ad1v[nt], pd1);
        }
#pragma unroll
        for (int o = 1; o < 16; o <<= 1) {
            ps0 += __shfl_xor(ps0, o);
            ps1 += __shfl_xor(ps1, o);
            pd0 += __shfl_xor(pd0, o);
            pd1 += __shfl_xor(pd1, o);
        }
        int node = n0 + lg * 4 + r;
        if (li == 0 && node < N) {
            alsrc[node * 2] = ps0;
            alsrc[node * 2 + 1] = ps1;
            aldst[node * 2] = pd0;
            aldst[node * 2 + 1] = pd1;
        }
    }
    // h1h pair write: even lane packs {own col, col+1 from lane+1}
#pragma unroll
    for (int nt = 0; nt < 8; nt++)
#pragma unroll
        for (int r = 0; r < 4; r++) {
            float v = acc[nt][r];
            float p = __shfl_down(v, 1);
            int node = n0 + lg * 4 + r;
            if ((l & 1) == 0 && node < N)
                h1h[(size_t)node * 64 + nt * 8 + (li >> 1)] = __floats2half2_rn(v, p);
        }
}

// ---------------- GEMM2 (MFMA): h2 = hf @ W2 + attention logits ----------------
__global__ __launch_bounds__(256) void k_gemm2(
    const float* __restrict__ hf, const _Float16* __restrict__ bp2,
    const float* __restrict__ as2, const float* __restrict__ ad2,
    __half2* __restrict__ h2h, float* __restrict__ alsrc, float* __restrict__ aldst,
    int N) {
    int w = threadIdx.x >> 6, l = threadIdx.x & 63;
    int n0 = blockIdx.x * 64 + w * 16;
    int li = l & 15, lg = l >> 4;
    int arow = n0 + li;
    f16x8 a[4];
#pragma unroll
    for (int ks = 0; ks < 4; ks++) {
        float4 p0 = make_float4(0, 0, 0, 0), p1 = make_float4(0, 0, 0, 0);
        if (arow < N) {
            const float4* src = (const float4*)(hf + (size_t)arow * 128 + ks * 32 + lg * 8);
            p0 = src[0];
            p1 = src[1];
        }
        f16x8 t;
        t[0] = (_Float16)p0.x; t[1] = (_Float16)p0.y; t[2] = (_Float16)p0.z; t[3] = (_Float16)p0.w;
        t[4] = (_Float16)p1.x; t[5] = (_Float16)p1.y; t[6] = (_Float16)p1.z; t[7] = (_Float16)p1.w;
        a[ks] = t;
    }
    f32x4 acc[3];
#pragma unroll
    for (int nt = 0; nt < 3; nt++) acc[nt] = (f32x4){0.f, 0.f, 0.f, 0.f};
    const f16x8* bp = (const f16x8*)bp2;
#pragma unroll
    for (int nt = 0; nt < 3; nt++)
#pragma unroll
        for (int ks = 0; ks < 4; ks++)
            acc[nt] = __builtin_amdgcn_mfma_f32_16x16x32_f16(a[ks], bp[(ks * 3 + nt) * 64 + l],
                                                             acc[nt], 0, 0, 0);
    float as2v[3], ad2v[3];
#pragma unroll
    for (int nt = 0; nt < 3; nt++) {
        int col = nt * 16 + li;
        as2v[nt] = (col < 40) ? as2[col] : 0.f;
        ad2v[nt] = (col < 40) ? ad2[col] : 0.f;
    }
#pragma unroll
    for (int r = 0; r < 4; r++) {
        float ps = 0, pd = 0;
#pragma unroll
        for (int nt = 0; nt < 3; nt++) {
            ps = fmaf(acc[nt][r], as2v[nt], ps);
            pd = fmaf(acc[nt][r], ad2v[nt], pd);
        }
#pragma unroll
        for (int o = 1; o < 16; o <<= 1) {
            ps += __shfl_xor(ps, o);
            pd += __shfl_xor(pd, o);
        }
        int node = n0 + lg * 4 + r;
        if (li == 0 && node < N) {
            alsrc[node] = ps;
            aldst[node] = pd;
        }
    }
#pragma unroll
    for (int nt = 0; nt < 3; nt++)
#pragma unroll
        for (int r = 0; r < 4; r++) {
            float v = acc[nt][r];
            float p = __shfl_down(v, 1);
            int node = n0 + lg * 4 + r;
            int col = nt * 16 + li;
            if ((l & 1) == 0 && col < 40 && node < N)
                h2h[(size_t)node * 20 + nt * 8 + (li >> 1)] = __floats2half2_rn(v, p);
        }
}

// ---------------- CSR build ----------------
__global__ void k_count(const int* __restrict__ ei, int* __restrict__ cnt, int E, int ET) {
    int e = blockIdx.x * blockDim.x + threadIdx.x;
    if (e >= ET) return;
    int d = (e < E) ? ei[E + e] : e - E;
    atomicAdd(&cnt[d], 1);
}

__global__ __launch_bounds__(256) void k_scan1(const int* __restrict__ cnt,
                                               int* __restrict__ loc,
                                               int* __restrict__ sums, int N) {
    __shared__ int sh[256];
    int i = blockIdx.x * 256 + threadIdx.x;
    int v = (i < N) ? cnt[i] : 0;
    sh[threadIdx.x] = v;
    __syncthreads();
    for (int o = 1; o < 256; o <<= 1) {
        int t = (threadIdx.x >= o) ? sh[threadIdx.x - o] : 0;
        __syncthreads();
        sh[threadIdx.x] += t;
        __syncthreads();
    }
    if (i < N) loc[i] = sh[threadIdx.x];
    if (threadIdx.x == 255) sums[blockIdx.x] = sh[255];
}

__global__ __launch_bounds__(256) void k_scan2(int* __restrict__ sums, int nb) {
    __shared__ int sh[256];
    int v = (threadIdx.x < nb) ? sums[threadIdx.x] : 0;
    sh[threadIdx.x] = v;
    __syncthreads();
    for (int o = 1; o < 256; o <<= 1) {
        int t = (threadIdx.x >= o) ? sh[threadIdx.x - o] : 0;
        __syncthreads();
        sh[threadIdx.x] += t;
        __syncthreads();
    }
    if (threadIdx.x < nb) sums[threadIdx.x] = sh[threadIdx.x] - v;  // exclusive
}

__global__ __launch_bounds__(256) void k_scan3(const int* __restrict__ cnt,
                                               const int* __restrict__ loc,
                                               const int* __restrict__ sums,
                                               int* __restrict__ rowptr,
                                               int* __restrict__ woff, int N, int ET) {
    int i = blockIdx.x * 256 + threadIdx.x;
    if (i == 0) rowptr[N] = ET;
    if (i >= N) return;
    int v = sums[blockIdx.x] + loc[i] - cnt[i];
    rowptr[i] = v;
    woff[i] = v;
}

__global__ void k_scatter(const int* __restrict__ ei, int* __restrict__ woff,
                          int* __restrict__ col, int E, int ET) {
    int e = blockIdx.x * blockDim.x + threadIdx.x;
    if (e >= ET) return;
    int s = (e < E) ? ei[e] : e - E;
    int d = (e < E) ? ei[E + e] : e - E;
    int pos = atomicAdd(&woff[d], 1);
    col[pos] = s;
}

// ---------------- fused gather layer 1 ----------------
__global__ __launch_bounds__(256) void k_gather1(
    const int* __restrict__ rowptr, const int* __restrict__ col,
    const __half2* __restrict__ h1h, const float2* __restrict__ alsrc,
    const float2* __restrict__ aldst, const float* __restrict__ b1,
    float2* __restrict__ hf2, int N) {
    int wid = (int)(((size_t)blockIdx.x * blockDim.x + threadIdx.x) >> 6);
    int lane = threadIdx.x & 63;
    if (wid >= N) return;
    int start = rowptr[wid], end = rowptr[wid + 1];
    float2 ad = aldst[wid];
    bool hl = lane < 32;
    float m0 = -1e30f, m1 = -1e30f, s0 = 0.f, s1 = 0.f, a0 = 0.f, a1 = 0.f;
    for (int base = start; base < end; base += 64) {
        int nb = min(64, end - base);
        int sv = 0;
        float l0 = -1e30f, l1 = -1e30f;
        if (lane < nb) {
            sv = col[base + lane];
            float2 asv = alsrc[sv];
            float t0 = asv.x + ad.x, t1 = asv.y + ad.y;
            l0 = (t0 > 0.f) ? t0 : NEG_SLOPE * t0;
            l1 = (t1 > 0.f) ? t1 : NEG_SLOPE * t1;
        }
        float c0 = l0, c1 = l1;
#pragma unroll
        for (int o = 32; o > 0; o >>= 1) {
            c0 = fmaxf(c0, __shfl_xor(c0, o));
            c1 = fmaxf(c1, __shfl_xor(c1, o));
        }
        float sc0 = 1.f, sc1 = 1.f;
        if (c0 > m0) { sc0 = __expf(m0 - c0); s0 *= sc0; m0 = c0; }
        if (c1 > m1) { sc1 = __expf(m1 - c1); s1 *= sc1; m1 = c1; }
        float msc = hl ? sc0 : sc1;
        a0 *= msc; a1 *= msc;
        float e0 = (lane < nb) ? __expf(l0 - m0) : 0.f;
        float e1 = (lane < nb) ? __expf(l1 - m1) : 0.f;
        float t0 = e0, t1 = e1;
#pragma unroll
        for (int o = 32; o > 0; o >>= 1) {
            t0 += __shfl_xor(t0, o);
            t1 += __shfl_xor(t1, o);
        }
        s0 += t0; s1 += t1;
        int j = 0;
        for (; j + 4 <= nb; j += 4) {
            int sA = __shfl(sv, j),     sB = __shfl(sv, j + 1),
                sC = __shfl(sv, j + 2), sD = __shfl(sv, j + 3);
            __half2 vA = h1h[(size_t)sA * 64 + lane];
            __half2 vB = h1h[(size_t)sB * 64 + lane];
            __half2 vC = h1h[(size_t)sC * 64 + lane];
            __half2 vD = h1h[(size_t)sD * 64 + lane];
            float wA0 = __shfl(e0, j),     wA1 = __shfl(e1, j);
            float wB0 = __shfl(e0, j + 1), wB1 = __shfl(e1, j + 1);
            float wC0 = __shfl(e0, j + 2), wC1 = __shfl(e1, j + 2);
            float wD0 = __shfl(e0, j + 3), wD1 = __shfl(e1, j + 3);
            float wA = hl ? wA0 : wA1, wB = hl ? wB0 : wB1;
            float wC = hl ? wC0 : wC1, wD = hl ? wD0 : wD1;
            float2 fA = __half22float2(vA), fB = __half22float2(vB);
            float2 fC = __half22float2(vC), fD = __half22float2(vD);
            a0 = fmaf(wA, fA.x, a0); a1 = fmaf(wA, fA.y, a1);
            a0 = fmaf(wB, fB.x, a0); a1 = fmaf(wB, fB.y, a1);
            a0 = fmaf(wC, fC.x, a0); a1 = fmaf(wC, fC.y, a1);
            a0 = fmaf(wD, fD.x, a0); a1 = fmaf(wD, fD.y, a1);
        }
        for (; j < nb; j++) {
            int s = __shfl(sv, j);
            float w0 = __shfl(e0, j), w1 = __shfl(e1, j);
            float w = hl ? w0 : w1;
            float2 f = __half22float2(h1h[(size_t)s * 64 + lane]);
            a0 = fmaf(w, f.x, a0);
            a1 = fmaf(w, f.y, a1);
        }
    }
    float denom = (hl ? s0 : s1) + 1e-16f;
    float v0 = a0 / denom + b1[2 * lane];
    float v1 = a1 / denom + b1[2 * lane + 1];
    v0 = (v0 > 0.f) ? v0 : expm1f(v0);
    v1 = (v1 > 0.f) ? v1 : expm1f(v1);
    hf2[(size_t)wid * 64 + lane] = make_float2(v0, v1);
}

// ---------------- fused gather layer 2 ----------------
__global__ __launch_bounds__(256) void k_gather2(
    const int* __restrict__ rowptr, const int* __restrict__ col,
    const __half2* __restrict__ h2h, const float* __restrict__ alsrc,
    const float* __restrict__ aldst, const float* __restrict__ b2,
    float2* __restrict__ out2, int N) {
    int wid = (int)(((size_t)blockIdx.x * blockDim.x + threadIdx.x) >> 6);
    int lane = threadIdx.x & 63;
    if (wid >= N) return;
    int start = rowptr[wid], end = rowptr[wid + 1];
    float ad = aldst[wid];
    int ln = (lane < 20) ? lane : 0;
    float m = -1e30f, s = 0.f, a0 = 0.f, a1 = 0.f;
    for (int base = start; base < end; base += 64) {
        int nb = min(64, end - base);
        int sv = 0;
        float l = -1e30f;
        if (lane < nb) {
            sv = col[base + lane];
            float t = alsrc[sv] + ad;
            l = (t > 0.f) ? t : NEG_SLOPE * t;
        }
        float c = l;
#pragma unroll
        for (int o = 32; o > 0; o >>= 1) c = fmaxf(c, __shfl_xor(c, o));
        if (c > m) { float sc = __expf(m - c); s *= sc; a0 *= sc; a1 *= sc; m = c; }
        float e = (lane < nb) ? __expf(l - m) : 0.f;
        float t = e;
#pragma unroll
        for (int o = 32; o > 0; o >>= 1) t += __shfl_xor(t, o);
        s += t;
        int j = 0;
        for (; j + 4 <= nb; j += 4) {
            int sA = __shfl(sv, j),     sB = __shfl(sv, j + 1),
                sC = __shfl(sv, j + 2), sD = __shfl(sv, j + 3);
            __half2 vA = h2h[(size_t)sA * 20 + ln];
            __half2 vB = h2h[(size_t)sB * 20 + ln];
            __half2 vC = h2h[(size_t)sC * 20 + ln];
            __half2 vD = h2h[(size_t)sD * 20 + ln];
            float wA = __shfl(e, j),     wB = __shfl(e, j + 1);
            float wC = __shfl(e, j + 2), wD = __shfl(e, j + 3);
            float2 fA = __half22float2(vA), fB = __half22float2(vB);
            float2 fC = __half22float2(vC), fD = __half22float2(vD);
            a0 = fmaf(wA, fA.x, a0); a1 = fmaf(wA, fA.y, a1);
            a0 = fmaf(wB, fB.x, a0); a1 = fmaf(wB, fB.y, a1);
            a0 = fmaf(wC, fC.x, a0); a1 = fmaf(wC, fC.y, a1);
            a0 = fmaf(wD, fD.x, a0); a1 = fmaf(wD, fD.y, a1);
        }
        for (; j < nb; j++) {
            int src = __shfl(sv, j);
            float w = __shfl(e, j);
            float2 f = __half22float2(h2h[(size_t)src * 20 + ln]);
            a0 = fmaf(w, f.x, a0);
            a1 = fmaf(w, f.y, a1);
        }
    }
    if (lane < 20) {
        float denom = s + 1e-16f;
        out2[(size_t)wid * 20 + lane] =
            make_float2(a0 / denom + b2[2 * lane], a1 / denom + b2[2 * lane + 1]);
    }
}

extern "C" void kernel_launch(void* const* d_in, const int* in_sizes, int n_in,
                              void* d_out, int out_size, void* d_ws, size_t ws_size,
                              hipStream_t stream) {
    const float* x   = (const float*)d_in[0];
    const int*   ei  = (const int*)d_in[1];
    const float* W1  = (const float*)d_in[2];
    const float* as1 = (const float*)d_in[3];
    const float* ad1 = (const float*)d_in[4];
    const float* b1  = (const float*)d_in[5];
    const float* W2  = (const float*)d_in[6];
    const float* as2 = (const float*)d_in[7];
    const float* ad2 = (const float*)d_in[8];
    const float* b2  = (const float*)d_in[9];
    int N = in_sizes[0] / 128;
    int E = in_sizes[1] / 2;
    int ET = E + N;
    float2* out2 = (float2*)d_out;

    char* ws = (char*)d_ws;
    size_t off = 0;
    auto alloc = [&](size_t bytes) {
        char* p = ws + off;
        off += (bytes + 255) & ~(size_t)255;
        return p;
    };
    int nb = (N + 255) / 256;
    int*      cnt    = (int*)alloc((size_t)N * 4);  // zero-init
    int*      loc    = (int*)alloc((size_t)N * 4);
    int*      sums   = (int*)alloc(256 * 4);
    int*      rowptr = (int*)alloc(((size_t)N + 1) * 4);
    int*      woff   = (int*)alloc((size_t)N * 4);
    int*      colbuf = (int*)alloc((size_t)ET * 4);
    _Float16* bp1    = (_Float16*)alloc(16384 * 2);
    _Float16* bp2    = (_Float16*)alloc(6144 * 2);
    __half2*  h1h    = (__half2*)alloc((size_t)N * 64 * 4);
    float*    hf     = (float*)alloc((size_t)N * 128 * 4);
    __half2*  h2h    = (__half2*)alloc((size_t)N * 20 * 4);
    float*    alsrc1 = (float*)alloc((size_t)N * 2 * 4);
    float*    aldst1 = (float*)alloc((size_t)N * 2 * 4);
    float*    alsrc2 = (float*)alloc((size_t)N * 4);
    float*    aldst2 = (float*)alloc((size_t)N * 4);

    hipMemsetAsync(cnt, 0, (size_t)N * 4, stream);

    dim3 b256(256);
    int gE = (ET + 255) / 256;

    // weight pack (independent of CSR)
    k_pack<<<(16384 + 6144 + 255) / 256, b256, 0, stream>>>(W1, W2, bp1, bp2);

    // CSR build (shared by both layers)
    k_count<<<gE, b256, 0, stream>>>(ei, cnt, E, ET);
    k_scan1<<<nb, b256, 0, stream>>>(cnt, loc, sums, N);
    k_scan2<<<1, b256, 0, stream>>>(sums, nb);
    k_scan3<<<nb, b256, 0, stream>>>(cnt, loc, sums, rowptr, woff, N, ET);
    k_scatter<<<gE, b256, 0, stream>>>(ei, woff, colbuf, E, ET);

    int gG = (N + 63) / 64;  // 64 nodes per block
    // layer 1
    k_gemm1<<<gG, b256, 0, stream>>>(x, bp1, as1, ad1, h1h, alsrc1, aldst1, N);
    k_gather1<<<(int)(((size_t)N * 64 + 255) / 256), b256, 0, stream>>>(
        rowptr, colbuf, h1h, (const float2*)alsrc1, (const float2*)aldst1, b1, (float2*)hf, N);

    // layer 2
    k_gemm2<<<gG, b256, 0, stream>>>(hf, bp2, as2, ad2, h2h, alsrc2, aldst2, N);
    k_gather2<<<(int)(((size_t)N * 64 + 255) / 256), b256, 0, stream>>>(
        rowptr, colbuf, h2h, alsrc2, aldst2, b2, out2, N);
}

// Round 6
// 149.160 us; speedup vs baseline: 2.3325x; 1.4101x over previous
//
#include <hip/hip_runtime.h>
#include <hip/hip_fp16.h>

#define NEG_SLOPE 0.2f

typedef _Float16 f16x8 __attribute__((ext_vector_type(8)));
typedef float f32x4 __attribute__((ext_vector_type(4)));

// ---------------- pack W1/W2 into MFMA B-fragment order (fp16) ----------------
__global__ __launch_bounds__(256) void k_pack(const float* __restrict__ W1,
                                              const float* __restrict__ W2,
                                              _Float16* __restrict__ bp1,
                                              _Float16* __restrict__ bp2) {
    int idx = blockIdx.x * 256 + threadIdx.x;
    if (idx < 16384) {  // W1: 4 ks * 8 nt * 64 * 8
        int j = idx & 7, l = (idx >> 3) & 63, nt = (idx >> 9) & 7, ks = idx >> 12;
        int k = ks * 32 + (l >> 4) * 8 + j;
        int col = nt * 16 + (l & 15);
        bp1[idx] = (_Float16)W1[k * 128 + col];
    }
    int idx2 = idx - 16384;
    if (idx2 >= 0 && idx2 < 6144) {  // W2: 4 ks * 3 nt * 64 * 8 (cols >=40 zero)
        int j = idx2 & 7, l = (idx2 >> 3) & 63, q = idx2 >> 9;
        int nt = q % 3, ks = q / 3;
        int k = ks * 32 + (l >> 4) * 8 + j;
        int col = nt * 16 + (l & 15);
        bp2[idx2] = (col < 40) ? (_Float16)W2[k * 40 + col] : (_Float16)0.f;
    }
}

// ---------------- one-pass ELL bucket build (replaces count+scan+scatter) ----
// 8 dst-range partitions; partition p handled by blocks with blockIdx&7==p
// (round-robin dispatch pins them to one XCD -> cnt/colell slices stay L2-local).
// Self-loops are NOT stored (handled analytically in the gathers).
__global__ void k_bucket(const int* __restrict__ ei, int* __restrict__ cnt,
                         int* __restrict__ colell, int E, int ps) {
    int p = blockIdx.x & 7;
    int e = (blockIdx.x >> 3) * blockDim.x + threadIdx.x;
    if (e >= E) return;
    int d = ei[E + e];
    int lo = p * ps;
    if (d < lo || d >= lo + ps) return;
    int s = ei[e];
    int rank = atomicAdd(&cnt[d], 1);
    if (rank < 64) colell[(size_t)d * 64 + rank] = s;
}

// ---------------- GEMM1 (MFMA): h1 = x @ W1 + attention logits ----------------
__global__ __launch_bounds__(256) void k_gemm1(
    const float* __restrict__ x, const _Float16* __restrict__ bp1,
    const float* __restrict__ as1, const float* __restrict__ ad1,
    __half2* __restrict__ h1h, float* __restrict__ alsrc, float* __restrict__ aldst,
    int N) {
    int w = threadIdx.x >> 6, l = threadIdx.x & 63;
    int n0 = blockIdx.x * 64 + w * 16;
    int li = l & 15, lg = l >> 4;
    int arow = n0 + li;
    f16x8 a[4];
#pragma unroll
    for (int ks = 0; ks < 4; ks++) {
        float4 p0 = make_float4(0, 0, 0, 0), p1 = make_float4(0, 0, 0, 0);
        if (arow < N) {
            const float4* src = (const float4*)(x + (size_t)arow * 128 + ks * 32 + lg * 8);
            p0 = src[0];
            p1 = src[1];
        }
        f16x8 t;
        t[0] = (_Float16)p0.x; t[1] = (_Float16)p0.y; t[2] = (_Float16)p0.z; t[3] = (_Float16)p0.w;
        t[4] = (_Float16)p1.x; t[5] = (_Float16)p1.y; t[6] = (_Float16)p1.z; t[7] = (_Float16)p1.w;
        a[ks] = t;
    }
    f32x4 acc[8];
#pragma unroll
    for (int nt = 0; nt < 8; nt++) acc[nt] = (f32x4){0.f, 0.f, 0.f, 0.f};
    const f16x8* bp = (const f16x8*)bp1;
#pragma unroll
    for (int nt = 0; nt < 8; nt++)
#pragma unroll
        for (int ks = 0; ks < 4; ks++)
            acc[nt] = __builtin_amdgcn_mfma_f32_16x16x32_f16(a[ks], bp[(ks * 8 + nt) * 64 + l],
                                                             acc[nt], 0, 0, 0);
    float as1v[8], ad1v[8];
#pragma unroll
    for (int nt = 0; nt < 8; nt++) {
        as1v[nt] = as1[nt * 16 + li];
        ad1v[nt] = ad1[nt * 16 + li];
    }
#pragma unroll
    for (int r = 0; r < 4; r++) {
        float ps0 = 0, ps1 = 0, pd0 = 0, pd1 = 0;
#pragma unroll
        for (int nt = 0; nt < 4; nt++) {
            ps0 = fmaf(acc[nt][r], as1v[nt], ps0);
            pd0 = fmaf(acc[nt][r], ad1v[nt], pd0);
        }
#pragma unroll
        for (int nt = 4; nt < 8; nt++) {
            ps1 = fmaf(acc[nt][r], as1v[nt], ps1);
            pd1 = fmaf(acc[nt][r], ad1v[nt], pd1);
        }
#pragma unroll
        for (int o = 1; o < 16; o <<= 1) {
            ps0 += __shfl_xor(ps0, o);
            ps1 += __shfl_xor(ps1, o);
            pd0 += __shfl_xor(pd0, o);
            pd1 += __shfl_xor(pd1, o);
        }
        int node = n0 + lg * 4 + r;
        if (li == 0 && node < N) {
            alsrc[node * 2] = ps0;
            alsrc[node * 2 + 1] = ps1;
            aldst[node * 2] = pd0;
            aldst[node * 2 + 1] = pd1;
        }
    }
#pragma unroll
    for (int nt = 0; nt < 8; nt++)
#pragma unroll
        for (int r = 0; r < 4; r++) {
            float v = acc[nt][r];
            float p = __shfl_down(v, 1);
            int node = n0 + lg * 4 + r;
            if ((l & 1) == 0 && node < N)
                h1h[(size_t)node * 64 + nt * 8 + (li >> 1)] = __floats2half2_rn(v, p);
        }
}

// ---------------- GEMM2 (MFMA): h2 = hf @ W2 + attention logits ----------------
__global__ __launch_bounds__(256) void k_gemm2(
    const float* __restrict__ hf, const _Float16* __restrict__ bp2,
    const float* __restrict__ as2, const float* __restrict__ ad2,
    __half2* __restrict__ h2h, float* __restrict__ alsrc, float* __restrict__ aldst,
    int N) {
    int w = threadIdx.x >> 6, l = threadIdx.x & 63;
    int n0 = blockIdx.x * 64 + w * 16;
    int li = l & 15, lg = l >> 4;
    int arow = n0 + li;
    f16x8 a[4];
#pragma unroll
    for (int ks = 0; ks < 4; ks++) {
        float4 p0 = make_float4(0, 0, 0, 0), p1 = make_float4(0, 0, 0, 0);
        if (arow < N) {
            const float4* src = (const float4*)(hf + (size_t)arow * 128 + ks * 32 + lg * 8);
            p0 = src[0];
            p1 = src[1];
        }
        f16x8 t;
        t[0] = (_Float16)p0.x; t[1] = (_Float16)p0.y; t[2] = (_Float16)p0.z; t[3] = (_Float16)p0.w;
        t[4] = (_Float16)p1.x; t[5] = (_Float16)p1.y; t[6] = (_Float16)p1.z; t[7] = (_Float16)p1.w;
        a[ks] = t;
    }
    f32x4 acc[3];
#pragma unroll
    for (int nt = 0; nt < 3; nt++) acc[nt] = (f32x4){0.f, 0.f, 0.f, 0.f};
    const f16x8* bp = (const f16x8*)bp2;
#pragma unroll
    for (int nt = 0; nt < 3; nt++)
#pragma unroll
        for (int ks = 0; ks < 4; ks++)
            acc[nt] = __builtin_amdgcn_mfma_f32_16x16x32_f16(a[ks], bp[(ks * 3 + nt) * 64 + l],
                                                             acc[nt], 0, 0, 0);
    float as2v[3], ad2v[3];
#pragma unroll
    for (int nt = 0; nt < 3; nt++) {
        int col = nt * 16 + li;
        as2v[nt] = (col < 40) ? as2[col] : 0.f;
        ad2v[nt] = (col < 40) ? ad2[col] : 0.f;
    }
#pragma unroll
    for (int r = 0; r < 4; r++) {
        float ps = 0, pd = 0;
#pragma unroll
        for (int nt = 0; nt < 3; nt++) {
            ps = fmaf(acc[nt][r], as2v[nt], ps);
            pd = fmaf(acc[nt][r], ad2v[nt], pd);
        }
#pragma unroll
        for (int o = 1; o < 16; o <<= 1) {
            ps += __shfl_xor(ps, o);
            pd += __shfl_xor(pd, o);
        }
        int node = n0 + lg * 4 + r;
        if (li == 0 && node < N) {
            alsrc[node] = ps;
            aldst[node] = pd;
        }
    }
#pragma unroll
    for (int nt = 0; nt < 3; nt++)
#pragma unroll
        for (int r = 0; r < 4; r++) {
            float v = acc[nt][r];
            float p = __shfl_down(v, 1);
            int node = n0 + lg * 4 + r;
            int col = nt * 16 + li;
            if ((l & 1) == 0 && col < 40 && node < N)
                h2h[(size_t)node * 20 + nt * 8 + (li >> 1)] = __floats2half2_rn(v, p);
        }
}

// ---------------- fused gather layer 1 (single ELL chunk + analytic self-loop) --
__global__ __launch_bounds__(256) void k_gather1(
    const int* __restrict__ cnt, const int* __restrict__ colell,
    const __half2* __restrict__ h1h, const float2* __restrict__ alsrc,
    const float2* __restrict__ aldst, const float* __restrict__ b1,
    float2* __restrict__ hf2, int N) {
    int wid = (int)(((size_t)blockIdx.x * blockDim.x + threadIdx.x) >> 6);
    int lane = threadIdx.x & 63;
    if (wid >= N) return;
    float2 asn = alsrc[wid], ad = aldst[wid];
    // self-loop seeds the online softmax: m = l_self, s = 1, a = h[self]
    float ls0 = asn.x + ad.x; ls0 = (ls0 > 0.f) ? ls0 : NEG_SLOPE * ls0;
    float ls1 = asn.y + ad.y; ls1 = (ls1 > 0.f) ? ls1 : NEG_SLOPE * ls1;
    bool hl = lane < 32;
    float m0 = ls0, m1 = ls1, s0 = 1.f, s1 = 1.f;
    float2 fs = __half22float2(h1h[(size_t)wid * 64 + lane]);
    float a0 = fs.x, a1 = fs.y;
    int nb = min(cnt[wid], 64);
    if (nb > 0) {
        int sv = 0;
        float l0 = -1e30f, l1 = -1e30f;
        if (lane < nb) {
            sv = colell[(size_t)wid * 64 + lane];
            float2 asv = alsrc[sv];
            float t0 = asv.x + ad.x, t1 = asv.y + ad.y;
            l0 = (t0 > 0.f) ? t0 : NEG_SLOPE * t0;
            l1 = (t1 > 0.f) ? t1 : NEG_SLOPE * t1;
        }
        float c0 = l0, c1 = l1;
#pragma unroll
        for (int o = 32; o > 0; o >>= 1) {
            c0 = fmaxf(c0, __shfl_xor(c0, o));
            c1 = fmaxf(c1, __shfl_xor(c1, o));
        }
        float sc0 = 1.f, sc1 = 1.f;
        if (c0 > m0) { sc0 = __expf(m0 - c0); s0 *= sc0; m0 = c0; }
        if (c1 > m1) { sc1 = __expf(m1 - c1); s1 *= sc1; m1 = c1; }
        float msc = hl ? sc0 : sc1;
        a0 *= msc; a1 *= msc;
        float e0 = (lane < nb) ? __expf(l0 - m0) : 0.f;
        float e1 = (lane < nb) ? __expf(l1 - m1) : 0.f;
        float t0 = e0, t1 = e1;
#pragma unroll
        for (int o = 32; o > 0; o >>= 1) {
            t0 += __shfl_xor(t0, o);
            t1 += __shfl_xor(t1, o);
        }
        s0 += t0; s1 += t1;
        int j = 0;
        for (; j + 4 <= nb; j += 4) {
            int sA = __shfl(sv, j),     sB = __shfl(sv, j + 1),
                sC = __shfl(sv, j + 2), sD = __shfl(sv, j + 3);
            __half2 vA = h1h[(size_t)sA * 64 + lane];
            __half2 vB = h1h[(size_t)sB * 64 + lane];
            __half2 vC = h1h[(size_t)sC * 64 + lane];
            __half2 vD = h1h[(size_t)sD * 64 + lane];
            float wA0 = __shfl(e0, j),     wA1 = __shfl(e1, j);
            float wB0 = __shfl(e0, j + 1), wB1 = __shfl(e1, j + 1);
            float wC0 = __shfl(e0, j + 2), wC1 = __shfl(e1, j + 2);
            float wD0 = __shfl(e0, j + 3), wD1 = __shfl(e1, j + 3);
            float wA = hl ? wA0 : wA1, wB = hl ? wB0 : wB1;
            float wC = hl ? wC0 : wC1, wD = hl ? wD0 : wD1;
            float2 fA = __half22float2(vA), fB = __half22float2(vB);
            float2 fC = __half22float2(vC), fD = __half22float2(vD);
            a0 = fmaf(wA, fA.x, a0); a1 = fmaf(wA, fA.y, a1);
            a0 = fmaf(wB, fB.x, a0); a1 = fmaf(wB, fB.y, a1);
            a0 = fmaf(wC, fC.x, a0); a1 = fmaf(wC, fC.y, a1);
            a0 = fmaf(wD, fD.x, a0); a1 = fmaf(wD, fD.y, a1);
        }
        for (; j < nb; j++) {
            int s = __shfl(sv, j);
            float w0 = __shfl(e0, j), w1 = __shfl(e1, j);
            float w = hl ? w0 : w1;
            float2 f = __half22float2(h1h[(size_t)s * 64 + lane]);
            a0 = fmaf(w, f.x, a0);
            a1 = fmaf(w, f.y, a1);
        }
    }
    float denom = (hl ? s0 : s1) + 1e-16f;
    float v0 = a0 / denom + b1[2 * lane];
    float v1 = a1 / denom + b1[2 * lane + 1];
    v0 = (v0 > 0.f) ? v0 : expm1f(v0);
    v1 = (v1 > 0.f) ? v1 : expm1f(v1);
    hf2[(size_t)wid * 64 + lane] = make_float2(v0, v1);
}

// ---------------- fused gather layer 2 (single ELL chunk + analytic self-loop) --
__global__ __launch_bounds__(256) void k_gather2(
    const int* __restrict__ cnt, const int* __restrict__ colell,
    const __half2* __restrict__ h2h, const float* __restrict__ alsrc,
    const float* __restrict__ aldst, const float* __restrict__ b2,
    float2* __restrict__ out2, int N) {
    int wid = (int)(((size_t)blockIdx.x * blockDim.x + threadIdx.x) >> 6);
    int lane = threadIdx.x & 63;
    if (wid >= N) return;
    float ad = aldst[wid];
    float ls = alsrc[wid] + ad; ls = (ls > 0.f) ? ls : NEG_SLOPE * ls;
    int ln = (lane < 20) ? lane : 0;
    float m = ls, s = 1.f;
    float2 fs = __half22float2(h2h[(size_t)wid * 20 + ln]);
    float a0 = fs.x, a1 = fs.y;
    int nb = min(cnt[wid], 64);
    if (nb > 0) {
        int sv = 0;
        float l = -1e30f;
        if (lane < nb) {
            sv = colell[(size_t)wid * 64 + lane];
            float t = alsrc[sv] + ad;
            l = (t > 0.f) ? t : NEG_SLOPE * t;
        }
        float c = l;
#pragma unroll
        for (int o = 32; o > 0; o >>= 1) c = fmaxf(c, __shfl_xor(c, o));
        if (c > m) { float sc = __expf(m - c); s *= sc; a0 *= sc; a1 *= sc; m = c; }
        float e = (lane < nb) ? __expf(l - m) : 0.f;
        float t = e;
#pragma unroll
        for (int o = 32; o > 0; o >>= 1) t += __shfl_xor(t, o);
        s += t;
        int j = 0;
        for (; j + 4 <= nb; j += 4) {
            int sA = __shfl(sv, j),     sB = __shfl(sv, j + 1),
                sC = __shfl(sv, j + 2), sD = __shfl(sv, j + 3);
            __half2 vA = h2h[(size_t)sA * 20 + ln];
            __half2 vB = h2h[(size_t)sB * 20 + ln];
            __half2 vC = h2h[(size_t)sC * 20 + ln];
            __half2 vD = h2h[(size_t)sD * 20 + ln];
            float wA = __shfl(e, j),     wB = __shfl(e, j + 1);
            float wC = __shfl(e, j + 2), wD = __shfl(e, j + 3);
            float2 fA = __half22float2(vA), fB = __half22float2(vB);
            float2 fC = __half22float2(vC), fD = __half22float2(vD);
            a0 = fmaf(wA, fA.x, a0); a1 = fmaf(wA, fA.y, a1);
            a0 = fmaf(wB, fB.x, a0); a1 = fmaf(wB, fB.y, a1);
            a0 = fmaf(wC, fC.x, a0); a1 = fmaf(wC, fC.y, a1);
            a0 = fmaf(wD, fD.x, a0); a1 = fmaf(wD, fD.y, a1);
        }
        for (; j < nb; j++) {
            int src = __shfl(sv, j);
            float w = __shfl(e, j);
            float2 f = __half22float2(h2h[(size_t)src * 20 + ln]);
            a0 = fmaf(w, f.x, a0);
            a1 = fmaf(w, f.y, a1);
        }
    }
    if (lane < 20) {
        float denom = s + 1e-16f;
        out2[(size_t)wid * 20 + lane] =
            make_float2(a0 / denom + b2[2 * lane], a1 / denom + b2[2 * lane + 1]);
    }
}

extern "C" void kernel_launch(void* const* d_in, const int* in_sizes, int n_in,
                              void* d_out, int out_size, void* d_ws, size_t ws_size,
                              hipStream_t stream) {
    const float* x   = (const float*)d_in[0];
    const int*   ei  = (const int*)d_in[1];
    const float* W1  = (const float*)d_in[2];
    const float* as1 = (const float*)d_in[3];
    const float* ad1 = (const float*)d_in[4];
    const float* b1  = (const float*)d_in[5];
    const float* W2  = (const float*)d_in[6];
    const float* as2 = (const float*)d_in[7];
    const float* ad2 = (const float*)d_in[8];
    const float* b2  = (const float*)d_in[9];
    int N = in_sizes[0] / 128;
    int E = in_sizes[1] / 2;
    float2* out2 = (float2*)d_out;

    char* ws = (char*)d_ws;
    size_t off = 0;
    auto alloc = [&](size_t bytes) {
        char* p = ws + off;
        off += (bytes + 255) & ~(size_t)255;
        return p;
    };
    int*      cnt    = (int*)alloc((size_t)N * 4);         // zero-init
    int*      colell = (int*)alloc((size_t)N * 64 * 4);    // ELL, stride 64
    _Float16* bp1    = (_Float16*)alloc(16384 * 2);
    _Float16* bp2    = (_Float16*)alloc(6144 * 2);
    __half2*  h1h    = (__half2*)alloc((size_t)N * 64 * 4);
    float*    hf     = (float*)alloc((size_t)N * 128 * 4);
    __half2*  h2h    = (__half2*)alloc((size_t)N * 20 * 4);
    float*    alsrc1 = (float*)alloc((size_t)N * 2 * 4);
    float*    aldst1 = (float*)alloc((size_t)N * 2 * 4);
    float*    alsrc2 = (float*)alloc((size_t)N * 4);
    float*    aldst2 = (float*)alloc((size_t)N * 4);

    hipMemsetAsync(cnt, 0, (size_t)N * 4, stream);

    dim3 b256(256);
    int ps = (N + 7) / 8;  // dst-partition size
    int gB = 8 * ((E + 255) / 256);

    k_pack<<<(16384 + 6144 + 255) / 256, b256, 0, stream>>>(W1, W2, bp1, bp2);
    k_bucket<<<gB, b256, 0, stream>>>(ei, cnt, colell, E, ps);

    int gG = (N + 63) / 64;  // 64 nodes per block
    // layer 1
    k_gemm1<<<gG, b256, 0, stream>>>(x, bp1, as1, ad1, h1h, alsrc1, aldst1, N);
    k_gather1<<<(int)(((size_t)N * 64 + 255) / 256), b256, 0, stream>>>(
        cnt, colell, h1h, (const float2*)alsrc1, (const float2*)aldst1, b1, (float2*)hf, N);

    // layer 2
    k_gemm2<<<gG, b256, 0, stream>>>(hf, bp2, as2, ad2, h2h, alsrc2, aldst2, N);
    k_gather2<<<(int)(((size_t)N * 64 + 255) / 256), b256, 0, stream>>>(
        cnt, colell, h2h, alsrc2, aldst2, b2, out2, N);
}

// Round 7
// 148.580 us; speedup vs baseline: 2.3416x; 1.0039x over previous
//
#include <hip/hip_runtime.h>
#include <hip/hip_fp16.h>

#define NEG_SLOPE 0.2f

typedef _Float16 f16x8 __attribute__((ext_vector_type(8)));
typedef _Float16 f16x4 __attribute__((ext_vector_type(4)));
typedef float f32x4 __attribute__((ext_vector_type(4)));

// ---------------- pack W1/W2 into MFMA B-fragment order (fp16) ----------------
__global__ __launch_bounds__(256) void k_pack(const float* __restrict__ W1,
                                              const float* __restrict__ W2,
                                              _Float16* __restrict__ bp1,
                                              _Float16* __restrict__ bp2) {
    int idx = blockIdx.x * 256 + threadIdx.x;
    if (idx < 16384) {  // W1: 4 ks * 8 nt * 64 * 8
        int j = idx & 7, l = (idx >> 3) & 63, nt = (idx >> 9) & 7, ks = idx >> 12;
        int k = ks * 32 + (l >> 4) * 8 + j;
        int col = nt * 16 + (l & 15);
        bp1[idx] = (_Float16)W1[k * 128 + col];
    }
    int idx2 = idx - 16384;
    if (idx2 >= 0 && idx2 < 6144) {  // W2: 4 ks * 3 nt * 64 * 8 (cols >=40 zero)
        int j = idx2 & 7, l = (idx2 >> 3) & 63, q = idx2 >> 9;
        int nt = q % 3, ks = q / 3;
        int k = ks * 32 + (l >> 4) * 8 + j;
        int col = nt * 16 + (l & 15);
        bp2[idx2] = (col < 40) ? (_Float16)W2[k * 40 + col] : (_Float16)0.f;
    }
}

// ---------------- one-pass ELL bucket build ----------------
// 8 dst-range partitions pinned round-robin to XCDs; self-loops analytic.
__global__ void k_bucket(const int* __restrict__ ei, int* __restrict__ cnt,
                         int* __restrict__ colell, int E, int ps) {
    int p = blockIdx.x & 7;
    int e = (blockIdx.x >> 3) * blockDim.x + threadIdx.x;
    if (e >= E) return;
    int d = ei[E + e];
    int lo = p * ps;
    if (d < lo || d >= lo + ps) return;
    int s = ei[e];
    int rank = atomicAdd(&cnt[d], 1);
    if (rank < 64) colell[(size_t)d * 64 + rank] = s;
}

// ---------------- GEMM1 (MFMA): h1 = x @ W1 + attention logits ----------------
// h1h = plain half layout [n][128] (written as adjacent-channel pairs)
__global__ __launch_bounds__(256) void k_gemm1(
    const float* __restrict__ x, const _Float16* __restrict__ bp1,
    const float* __restrict__ as1, const float* __restrict__ ad1,
    __half2* __restrict__ h1h, float* __restrict__ alsrc, float* __restrict__ aldst,
    int N) {
    int w = threadIdx.x >> 6, l = threadIdx.x & 63;
    int n0 = blockIdx.x * 64 + w * 16;
    int li = l & 15, lg = l >> 4;
    int arow = n0 + li;
    f16x8 a[4];
#pragma unroll
    for (int ks = 0; ks < 4; ks++) {
        float4 p0 = make_float4(0, 0, 0, 0), p1 = make_float4(0, 0, 0, 0);
        if (arow < N) {
            const float4* src = (const float4*)(x + (size_t)arow * 128 + ks * 32 + lg * 8);
            p0 = src[0];
            p1 = src[1];
        }
        f16x8 t;
        t[0] = (_Float16)p0.x; t[1] = (_Float16)p0.y; t[2] = (_Float16)p0.z; t[3] = (_Float16)p0.w;
        t[4] = (_Float16)p1.x; t[5] = (_Float16)p1.y; t[6] = (_Float16)p1.z; t[7] = (_Float16)p1.w;
        a[ks] = t;
    }
    f32x4 acc[8];
#pragma unroll
    for (int nt = 0; nt < 8; nt++) acc[nt] = (f32x4){0.f, 0.f, 0.f, 0.f};
    const f16x8* bp = (const f16x8*)bp1;
#pragma unroll
    for (int nt = 0; nt < 8; nt++)
#pragma unroll
        for (int ks = 0; ks < 4; ks++)
            acc[nt] = __builtin_amdgcn_mfma_f32_16x16x32_f16(a[ks], bp[(ks * 8 + nt) * 64 + l],
                                                             acc[nt], 0, 0, 0);
    float as1v[8], ad1v[8];
#pragma unroll
    for (int nt = 0; nt < 8; nt++) {
        as1v[nt] = as1[nt * 16 + li];
        ad1v[nt] = ad1[nt * 16 + li];
    }
#pragma unroll
    for (int r = 0; r < 4; r++) {
        float ps0 = 0, ps1 = 0, pd0 = 0, pd1 = 0;
#pragma unroll
        for (int nt = 0; nt < 4; nt++) {
            ps0 = fmaf(acc[nt][r], as1v[nt], ps0);
            pd0 = fmaf(acc[nt][r], ad1v[nt], pd0);
        }
#pragma unroll
        for (int nt = 4; nt < 8; nt++) {
            ps1 = fmaf(acc[nt][r], as1v[nt], ps1);
            pd1 = fmaf(acc[nt][r], ad1v[nt], pd1);
        }
#pragma unroll
        for (int o = 1; o < 16; o <<= 1) {
            ps0 += __shfl_xor(ps0, o);
            ps1 += __shfl_xor(ps1, o);
            pd0 += __shfl_xor(pd0, o);
            pd1 += __shfl_xor(pd1, o);
        }
        int node = n0 + lg * 4 + r;
        if (li == 0 && node < N) {
            alsrc[node * 2] = ps0;
            alsrc[node * 2 + 1] = ps1;
            aldst[node * 2] = pd0;
            aldst[node * 2 + 1] = pd1;
        }
    }
#pragma unroll
    for (int nt = 0; nt < 8; nt++)
#pragma unroll
        for (int r = 0; r < 4; r++) {
            float v = acc[nt][r];
            float p = __shfl_down(v, 1);
            int node = n0 + lg * 4 + r;
            if ((l & 1) == 0 && node < N)
                h1h[(size_t)node * 64 + nt * 8 + (li >> 1)] = __floats2half2_rn(v, p);
        }
}

// ---------------- GEMM2 (MFMA): h2 = hf(fp16) @ W2 + attention logits --------
__global__ __launch_bounds__(256) void k_gemm2(
    const _Float16* __restrict__ hf, const _Float16* __restrict__ bp2,
    const float* __restrict__ as2, const float* __restrict__ ad2,
    __half2* __restrict__ h2h, float* __restrict__ alsrc, float* __restrict__ aldst,
    int N) {
    int w = threadIdx.x >> 6, l = threadIdx.x & 63;
    int n0 = blockIdx.x * 64 + w * 16;
    int li = l & 15, lg = l >> 4;
    int arow = n0 + li;
    const f16x8* hfv = (const f16x8*)hf;
    f16x8 a[4];
#pragma unroll
    for (int ks = 0; ks < 4; ks++) {
        f16x8 t;
        if (arow < N) {
            t = hfv[(size_t)arow * 16 + ks * 4 + lg];
        } else {
#pragma unroll
            for (int k = 0; k < 8; k++) t[k] = (_Float16)0.f;
        }
        a[ks] = t;
    }
    f32x4 acc[3];
#pragma unroll
    for (int nt = 0; nt < 3; nt++) acc[nt] = (f32x4){0.f, 0.f, 0.f, 0.f};
    const f16x8* bp = (const f16x8*)bp2;
#pragma unroll
    for (int nt = 0; nt < 3; nt++)
#pragma unroll
        for (int ks = 0; ks < 4; ks++)
            acc[nt] = __builtin_amdgcn_mfma_f32_16x16x32_f16(a[ks], bp[(ks * 3 + nt) * 64 + l],
                                                             acc[nt], 0, 0, 0);
    float as2v[3], ad2v[3];
#pragma unroll
    for (int nt = 0; nt < 3; nt++) {
        int col = nt * 16 + li;
        as2v[nt] = (col < 40) ? as2[col] : 0.f;
        ad2v[nt] = (col < 40) ? ad2[col] : 0.f;
    }
#pragma unroll
    for (int r = 0; r < 4; r++) {
        float ps = 0, pd = 0;
#pragma unroll
        for (int nt = 0; nt < 3; nt++) {
            ps = fmaf(acc[nt][r], as2v[nt], ps);
            pd = fmaf(acc[nt][r], ad2v[nt], pd);
        }
#pragma unroll
        for (int o = 1; o < 16; o <<= 1) {
            ps += __shfl_xor(ps, o);
            pd += __shfl_xor(pd, o);
        }
        int node = n0 + lg * 4 + r;
        if (li == 0 && node < N) {
            alsrc[node] = ps;
            aldst[node] = pd;
        }
    }
#pragma unroll
    for (int nt = 0; nt < 3; nt++)
#pragma unroll
        for (int r = 0; r < 4; r++) {
            float v = acc[nt][r];
            float p = __shfl_down(v, 1);
            int node = n0 + lg * 4 + r;
            int col = nt * 16 + li;
            if ((l & 1) == 0 && col < 40 && node < N)
                h2h[(size_t)node * 20 + nt * 8 + (li >> 1)] = __floats2half2_rn(v, p);
        }
}

// ---------------- fused gather layer 1: 16-lane edge groups ----------------
// group g=lane>>4 handles edge j+g; lane r=lane&15 owns channels 8r..8r+7 (16B f16x8)
__global__ __launch_bounds__(256) void k_gather1(
    const int* __restrict__ cnt, const int* __restrict__ colell,
    const f16x8* __restrict__ h1v, const float2* __restrict__ alsrc,
    const float2* __restrict__ aldst, const float4* __restrict__ b1v,
    _Float16* __restrict__ hf, int N) {
    int wid = (int)(((size_t)blockIdx.x * blockDim.x + threadIdx.x) >> 6);
    int lane = threadIdx.x & 63;
    if (wid >= N) return;
    int g = lane >> 4, r = lane & 15;
    float2 asn = alsrc[wid], ad = aldst[wid];
    float ls0 = asn.x + ad.x; ls0 = (ls0 > 0.f) ? ls0 : NEG_SLOPE * ls0;
    float ls1 = asn.y + ad.y; ls1 = (ls1 > 0.f) ? ls1 : NEG_SLOPE * ls1;
    float m0 = ls0, m1 = ls1, s0 = 1.f, s1 = 1.f;
    float a[8];
    {   // self-loop seed (group 0 only)
        f16x8 hs = h1v[(size_t)wid * 16 + r];
#pragma unroll
        for (int k = 0; k < 8; k++) a[k] = (g == 0) ? (float)hs[k] : 0.f;
    }
    int nb = min(cnt[wid], 64);
    if (nb > 0) {
        int sv = 0;
        float l0 = -1e30f, l1 = -1e30f;
        if (lane < nb) {
            sv = colell[(size_t)wid * 64 + lane];
            float2 asv = alsrc[sv];
            float t0 = asv.x + ad.x, t1 = asv.y + ad.y;
            l0 = (t0 > 0.f) ? t0 : NEG_SLOPE * t0;
            l1 = (t1 > 0.f) ? t1 : NEG_SLOPE * t1;
        }
        float c0 = l0, c1 = l1;
#pragma unroll
        for (int o = 32; o > 0; o >>= 1) {
            c0 = fmaxf(c0, __shfl_xor(c0, o));
            c1 = fmaxf(c1, __shfl_xor(c1, o));
        }
        float sc0 = 1.f, sc1 = 1.f;
        if (c0 > m0) { sc0 = __expf(m0 - c0); s0 *= sc0; m0 = c0; }
        if (c1 > m1) { sc1 = __expf(m1 - c1); s1 *= sc1; m1 = c1; }
        float asc = (r < 8) ? sc0 : sc1;
#pragma unroll
        for (int k = 0; k < 8; k++) a[k] *= asc;
        float e0 = (lane < nb) ? __expf(l0 - m0) : 0.f;
        float e1 = (lane < nb) ? __expf(l1 - m1) : 0.f;
        float t0 = e0, t1 = e1;
#pragma unroll
        for (int o = 32; o > 0; o >>= 1) {
            t0 += __shfl_xor(t0, o);
            t1 += __shfl_xor(t1, o);
        }
        s0 += t0; s1 += t1;
        for (int j = 0; j < nb; j += 4) {
            int ej = j + g;
            int src = __shfl(sv, ej);
            float w0 = __shfl(e0, ej), w1 = __shfl(e1, ej);
            float w = (r < 8) ? w0 : w1;
            if (ej < nb) {
                f16x8 h8 = h1v[(size_t)src * 16 + r];
#pragma unroll
                for (int k = 0; k < 8; k++) a[k] = fmaf(w, (float)h8[k], a[k]);
            }
        }
    }
    // cross-group reduce (4 partial sums of same channels)
#pragma unroll
    for (int k = 0; k < 8; k++) {
        a[k] += __shfl_xor(a[k], 16);
        a[k] += __shfl_xor(a[k], 32);
    }
    if (g == 0) {
        float inv = 1.f / (((r < 8) ? s0 : s1) + 1e-16f);
        float4 bA = b1v[2 * r], bB = b1v[2 * r + 1];
        float vb[8] = {bA.x, bA.y, bA.z, bA.w, bB.x, bB.y, bB.z, bB.w};
        f16x8 o;
#pragma unroll
        for (int k = 0; k < 8; k++) {
            float v = fmaf(a[k], inv, vb[k]);
            v = (v > 0.f) ? v : expm1f(v);  // ELU
            o[k] = (_Float16)v;
        }
        *(f16x8*)(hf + (size_t)wid * 128 + 8 * r) = o;
    }
}

// ---------------- fused gather layer 2: 16-lane edge groups ----------------
// lane r<10 owns channels 4r..4r+3 (8B f16x4)
__global__ __launch_bounds__(256) void k_gather2(
    const int* __restrict__ cnt, const int* __restrict__ colell,
    const f16x4* __restrict__ h2v, const float* __restrict__ alsrc,
    const float* __restrict__ aldst, const float4* __restrict__ b2v,
    float4* __restrict__ out4, int N) {
    int wid = (int)(((size_t)blockIdx.x * blockDim.x + threadIdx.x) >> 6);
    int lane = threadIdx.x & 63;
    if (wid >= N) return;
    int g = lane >> 4, r = lane & 15;
    float ad = aldst[wid];
    float ls = alsrc[wid] + ad; ls = (ls > 0.f) ? ls : NEG_SLOPE * ls;
    float m = ls, s = 1.f;
    float a[4] = {0.f, 0.f, 0.f, 0.f};
    if (g == 0 && r < 10) {
        f16x4 hs = h2v[(size_t)wid * 10 + r];
#pragma unroll
        for (int k = 0; k < 4; k++) a[k] = (float)hs[k];
    }
    int nb = min(cnt[wid], 64);
    if (nb > 0) {
        int sv = 0;
        float l = -1e30f;
        if (lane < nb) {
            sv = colell[(size_t)wid * 64 + lane];
            float t = alsrc[sv] + ad;
            l = (t > 0.f) ? t : NEG_SLOPE * t;
        }
        float c = l;
#pragma unroll
        for (int o = 32; o > 0; o >>= 1) c = fmaxf(c, __shfl_xor(c, o));
        if (c > m) {
            float sc = __expf(m - c);
            s *= sc; m = c;
#pragma unroll
            for (int k = 0; k < 4; k++) a[k] *= sc;
        }
        float e = (lane < nb) ? __expf(l - m) : 0.f;
        float t = e;
#pragma unroll
        for (int o = 32; o > 0; o >>= 1) t += __shfl_xor(t, o);
        s += t;
        for (int j = 0; j < nb; j += 4) {
            int ej = j + g;
            int src = __shfl(sv, ej);
            float w = __shfl(e, ej);
            if (ej < nb && r < 10) {
                f16x4 h4 = h2v[(size_t)src * 10 + r];
#pragma unroll
                for (int k = 0; k < 4; k++) a[k] = fmaf(w, (float)h4[k], a[k]);
            }
        }
    }
#pragma unroll
    for (int k = 0; k < 4; k++) {
        a[k] += __shfl_xor(a[k], 16);
        a[k] += __shfl_xor(a[k], 32);
    }
    if (g == 0 && r < 10) {
        float inv = 1.f / (s + 1e-16f);
        float4 b = b2v[r];
        float4 o = make_float4(fmaf(a[0], inv, b.x), fmaf(a[1], inv, b.y),
                               fmaf(a[2], inv, b.z), fmaf(a[3], inv, b.w));
        out4[(size_t)wid * 10 + r] = o;
    }
}

extern "C" void kernel_launch(void* const* d_in, const int* in_sizes, int n_in,
                              void* d_out, int out_size, void* d_ws, size_t ws_size,
                              hipStream_t stream) {
    const float* x   = (const float*)d_in[0];
    const int*   ei  = (const int*)d_in[1];
    const float* W1  = (const float*)d_in[2];
    const float* as1 = (const float*)d_in[3];
    const float* ad1 = (const float*)d_in[4];
    const float* b1  = (const float*)d_in[5];
    const float* W2  = (const float*)d_in[6];
    const float* as2 = (const float*)d_in[7];
    const float* ad2 = (const float*)d_in[8];
    const float* b2  = (const float*)d_in[9];
    int N = in_sizes[0] / 128;
    int E = in_sizes[1] / 2;
    float4* out4 = (float4*)d_out;

    char* ws = (char*)d_ws;
    size_t off = 0;
    auto alloc = [&](size_t bytes) {
        char* p = ws + off;
        off += (bytes + 255) & ~(size_t)255;
        return p;
    };
    int*      cnt    = (int*)alloc((size_t)N * 4);       // zero-init
    int*      colell = (int*)alloc((size_t)N * 64 * 4);  // ELL, stride 64
    _Float16* bp1    = (_Float16*)alloc(16384 * 2);
    _Float16* bp2    = (_Float16*)alloc(6144 * 2);
    __half2*  h1h    = (__half2*)alloc((size_t)N * 64 * 4);   // plain half [N][128]
    _Float16* hf     = (_Float16*)alloc((size_t)N * 128 * 2); // fp16 [N][128]
    __half2*  h2h    = (__half2*)alloc((size_t)N * 20 * 4);   // plain half [N][40]
    float*    alsrc1 = (float*)alloc((size_t)N * 2 * 4);
    float*    aldst1 = (float*)alloc((size_t)N * 2 * 4);
    float*    alsrc2 = (float*)alloc((size_t)N * 4);
    float*    aldst2 = (float*)alloc((size_t)N * 4);

    hipMemsetAsync(cnt, 0, (size_t)N * 4, stream);

    dim3 b256(256);
    int ps = (N + 7) / 8;
    int gB = 8 * ((E + 255) / 256);

    k_pack<<<(16384 + 6144 + 255) / 256, b256, 0, stream>>>(W1, W2, bp1, bp2);
    k_bucket<<<gB, b256, 0, stream>>>(ei, cnt, colell, E, ps);

    int gG = (N + 63) / 64;
    // layer 1
    k_gemm1<<<gG, b256, 0, stream>>>(x, bp1, as1, ad1, h1h, alsrc1, aldst1, N);
    k_gather1<<<(int)(((size_t)N * 64 + 255) / 256), b256, 0, stream>>>(
        cnt, colell, (const f16x8*)h1h, (const float2*)alsrc1, (const float2*)aldst1,
        (const float4*)b1, hf, N);

    // layer 2
    k_gemm2<<<gG, b256, 0, stream>>>(hf, bp2, as2, ad2, h2h, alsrc2, aldst2, N);
    k_gather2<<<(int)(((size_t)N * 64 + 255) / 256), b256, 0, stream>>>(
        cnt, colell, (const f16x4*)h2h, alsrc2, aldst2, (const float4*)b2, out4, N);
}

// Round 9
// 134.093 us; speedup vs baseline: 2.5945x; 1.1080x over previous
//
#include <hip/hip_runtime.h>
#include <hip/hip_fp16.h>

#define NEG_SLOPE 0.2f

typedef _Float16 f16x8 __attribute__((ext_vector_type(8)));
typedef float f32x4 __attribute__((ext_vector_type(4)));

__device__ __forceinline__ int h2i(__half2 h) { return *(int*)&h; }
__device__ __forceinline__ __half2 i2h(int i) { return *(__half2*)&i; }
__device__ __forceinline__ float lrelu(float v) { return (v > 0.f) ? v : NEG_SLOPE * v; }
__device__ __forceinline__ int pkmax(int a, int b) {
    int r;
    asm("v_pk_max_f16 %0, %1, %2" : "=v"(r) : "v"(a), "v"(b));
    return r;
}

union U16x8 { uint4 u; __half2 h[4]; };
union U16x4 { uint2 u; __half2 h[2]; };

// ---------------- pack W1/W2 into MFMA B-fragment order (fp16) ----------------
__global__ __launch_bounds__(256) void k_pack(const float* __restrict__ W1,
                                              const float* __restrict__ W2,
                                              _Float16* __restrict__ bp1,
                                              _Float16* __restrict__ bp2) {
    int idx = blockIdx.x * 256 + threadIdx.x;
    if (idx < 16384) {  // W1: 4 ks * 8 nt * 64 * 8
        int j = idx & 7, l = (idx >> 3) & 63, nt = (idx >> 9) & 7, ks = idx >> 12;
        int k = ks * 32 + (l >> 4) * 8 + j;
        int col = nt * 16 + (l & 15);
        bp1[idx] = (_Float16)W1[k * 128 + col];
    }
    int idx2 = idx - 16384;
    if (idx2 >= 0 && idx2 < 6144) {  // W2: 4 ks * 3 nt * 64 * 8 (cols >=40 zero)
        int j = idx2 & 7, l = (idx2 >> 3) & 63, q = idx2 >> 9;
        int nt = q % 3, ks = q / 3;
        int k = ks * 32 + (l >> 4) * 8 + j;
        int col = nt * 16 + (l & 15);
        bp2[idx2] = (col < 40) ? (_Float16)W2[k * 40 + col] : (_Float16)0.f;
    }
}

// ---------------- one-pass ELL bucket build ----------------
__global__ void k_bucket(const int* __restrict__ ei, int* __restrict__ cnt,
                         int* __restrict__ colell, int E, int ps) {
    int p = blockIdx.x & 7;
    int e = (blockIdx.x >> 3) * blockDim.x + threadIdx.x;
    if (e >= E) return;
    int d = ei[E + e];
    int lo = p * ps;
    if (d < lo || d >= lo + ps) return;
    int s = ei[e];
    int rank = atomicAdd(&cnt[d], 1);
    if (rank < 64) colell[(size_t)d * 64 + rank] = s;
}

// ---------------- GEMM1 (MFMA): h1 = x @ W1 + attention logits ----------------
__global__ __launch_bounds__(256) void k_gemm1(
    const float* __restrict__ x, const _Float16* __restrict__ bp1,
    const float* __restrict__ as1, const float* __restrict__ ad1,
    __half2* __restrict__ h1h, float* __restrict__ alsrc, float* __restrict__ aldst,
    int N) {
    int w = threadIdx.x >> 6, l = threadIdx.x & 63;
    int n0 = blockIdx.x * 64 + w * 16;
    int li = l & 15, lg = l >> 4;
    int arow = n0 + li;
    f16x8 a[4];
#pragma unroll
    for (int ks = 0; ks < 4; ks++) {
        float4 p0 = make_float4(0, 0, 0, 0), p1 = make_float4(0, 0, 0, 0);
        if (arow < N) {
            const float4* src = (const float4*)(x + (size_t)arow * 128 + ks * 32 + lg * 8);
            p0 = src[0];
            p1 = src[1];
        }
        f16x8 t;
        t[0] = (_Float16)p0.x; t[1] = (_Float16)p0.y; t[2] = (_Float16)p0.z; t[3] = (_Float16)p0.w;
        t[4] = (_Float16)p1.x; t[5] = (_Float16)p1.y; t[6] = (_Float16)p1.z; t[7] = (_Float16)p1.w;
        a[ks] = t;
    }
    f32x4 acc[8];
#pragma unroll
    for (int nt = 0; nt < 8; nt++) acc[nt] = (f32x4){0.f, 0.f, 0.f, 0.f};
    const f16x8* bp = (const f16x8*)bp1;
#pragma unroll
    for (int nt = 0; nt < 8; nt++)
#pragma unroll
        for (int ks = 0; ks < 4; ks++)
            acc[nt] = __builtin_amdgcn_mfma_f32_16x16x32_f16(a[ks], bp[(ks * 8 + nt) * 64 + l],
                                                             acc[nt], 0, 0, 0);
    float as1v[8], ad1v[8];
#pragma unroll
    for (int nt = 0; nt < 8; nt++) {
        as1v[nt] = as1[nt * 16 + li];
        ad1v[nt] = ad1[nt * 16 + li];
    }
#pragma unroll
    for (int r = 0; r < 4; r++) {
        float ps0 = 0, ps1 = 0, pd0 = 0, pd1 = 0;
#pragma unroll
        for (int nt = 0; nt < 4; nt++) {
            ps0 = fmaf(acc[nt][r], as1v[nt], ps0);
            pd0 = fmaf(acc[nt][r], ad1v[nt], pd0);
        }
#pragma unroll
        for (int nt = 4; nt < 8; nt++) {
            ps1 = fmaf(acc[nt][r], as1v[nt], ps1);
            pd1 = fmaf(acc[nt][r], ad1v[nt], pd1);
        }
#pragma unroll
        for (int o = 1; o < 16; o <<= 1) {
            ps0 += __shfl_xor(ps0, o);
            ps1 += __shfl_xor(ps1, o);
            pd0 += __shfl_xor(pd0, o);
            pd1 += __shfl_xor(pd1, o);
        }
        int node = n0 + lg * 4 + r;
        if (li == 0 && node < N) {
            alsrc[node * 2] = ps0;
            alsrc[node * 2 + 1] = ps1;
            aldst[node * 2] = pd0;
            aldst[node * 2 + 1] = pd1;
        }
    }
#pragma unroll
    for (int nt = 0; nt < 8; nt++)
#pragma unroll
        for (int r = 0; r < 4; r++) {
            float v = acc[nt][r];
            float p = __shfl_down(v, 1);
            int node = n0 + lg * 4 + r;
            if ((l & 1) == 0 && node < N)
                h1h[(size_t)node * 64 + nt * 8 + (li >> 1)] = __floats2half2_rn(v, p);
        }
}

// ---------------- GEMM2 (MFMA): h2 = hf(fp16) @ W2 + attention logits --------
__global__ __launch_bounds__(256) void k_gemm2(
    const _Float16* __restrict__ hf, const _Float16* __restrict__ bp2,
    const float* __restrict__ as2, const float* __restrict__ ad2,
    __half2* __restrict__ h2h, float* __restrict__ alsrc, float* __restrict__ aldst,
    int N) {
    int w = threadIdx.x >> 6, l = threadIdx.x & 63;
    int n0 = blockIdx.x * 64 + w * 16;
    int li = l & 15, lg = l >> 4;
    int arow = n0 + li;
    const f16x8* hfv = (const f16x8*)hf;
    f16x8 a[4];
#pragma unroll
    for (int ks = 0; ks < 4; ks++) {
        f16x8 t;
        if (arow < N) {
            t = hfv[(size_t)arow * 16 + ks * 4 + lg];
        } else {
#pragma unroll
            for (int k = 0; k < 8; k++) t[k] = (_Float16)0.f;
        }
        a[ks] = t;
    }
    f32x4 acc[3];
#pragma unroll
    for (int nt = 0; nt < 3; nt++) acc[nt] = (f32x4){0.f, 0.f, 0.f, 0.f};
    const f16x8* bp = (const f16x8*)bp2;
#pragma unroll
    for (int nt = 0; nt < 3; nt++)
#pragma unroll
        for (int ks = 0; ks < 4; ks++)
            acc[nt] = __builtin_amdgcn_mfma_f32_16x16x32_f16(a[ks], bp[(ks * 3 + nt) * 64 + l],
                                                             acc[nt], 0, 0, 0);
    float as2v[3], ad2v[3];
#pragma unroll
    for (int nt = 0; nt < 3; nt++) {
        int col = nt * 16 + li;
        as2v[nt] = (col < 40) ? as2[col] : 0.f;
        ad2v[nt] = (col < 40) ? ad2[col] : 0.f;
    }
#pragma unroll
    for (int r = 0; r < 4; r++) {
        float ps = 0, pd = 0;
#pragma unroll
        for (int nt = 0; nt < 3; nt++) {
            ps = fmaf(acc[nt][r], as2v[nt], ps);
            pd = fmaf(acc[nt][r], ad2v[nt], pd);
        }
#pragma unroll
        for (int o = 1; o < 16; o <<= 1) {
            ps += __shfl_xor(ps, o);
            pd += __shfl_xor(pd, o);
        }
        int node = n0 + lg * 4 + r;
        if (li == 0 && node < N) {
            alsrc[node] = ps;
            aldst[node] = pd;
        }
    }
#pragma unroll
    for (int nt = 0; nt < 3; nt++)
#pragma unroll
        for (int r = 0; r < 4; r++) {
            float v = acc[nt][r];
            float p = __shfl_down(v, 1);
            int node = n0 + lg * 4 + r;
            int col = nt * 16 + li;
            if ((l & 1) == 0 && col < 40 && node < N)
                h2h[(size_t)node * 20 + nt * 8 + (li >> 1)] = __floats2half2_rn(v, p);
        }
}

// ---------------- fused gather layer 1: packed-fp16 math ----------------
// group g=lane>>4 handles edges j+g; lane r=lane&15 owns channels 8r..8r+7
__global__ __launch_bounds__(256) void k_gather1(
    const int* __restrict__ cnt, const int* __restrict__ colell,
    const _Float16* __restrict__ h1, const float2* __restrict__ alsrc,
    const float2* __restrict__ aldst, const float4* __restrict__ b1v,
    _Float16* __restrict__ hf, int N) {
    int wid = (int)(((size_t)blockIdx.x * blockDim.x + threadIdx.x) >> 6);
    int lane = threadIdx.x & 63;
    if (wid >= N) return;
    int g = lane >> 4, r = lane & 15;
    float2 asn = alsrc[wid], ad = aldst[wid];
    float ls0 = lrelu(asn.x + ad.x);
    float ls1 = lrelu(asn.y + ad.y);
    int nb = min(cnt[wid], 64);
    // per-edge logits (lane = edge slot)
    int sv = 0;
    float l0 = -1e30f, l1 = -1e30f;
    if (lane < nb) {
        sv = colell[(size_t)wid * 64 + lane];
        float2 av = alsrc[sv];
        l0 = lrelu(av.x + ad.x);
        l1 = lrelu(av.y + ad.y);
    }
    // packed max reduce over 64 lanes (both heads at once)
    int lpi = h2i(__floats2half2_rn(l0, l1));
#pragma unroll
    for (int o = 32; o > 0; o >>= 1) lpi = pkmax(lpi, __shfl_xor(lpi, o));
    __half2 lp = i2h(lpi);
    float m0 = fmaxf(__low2float(lp), ls0);
    float m1 = fmaxf(__high2float(lp), ls1);
    float e0 = (lane < nb) ? __expf(l0 - m0) : 0.f;
    float e1 = (lane < nb) ? __expf(l1 - m1) : 0.f;
    int we = h2i(__floats2half2_rn(e0, e1));  // packed weights, one shfl for both heads
    // self-loop seed
    float lsh = (r < 8) ? ls0 : ls1;
    float mh = (r < 8) ? m0 : m1;
    __half esh = __float2half((g == 0) ? __expf(lsh - mh) : 0.f);
    float s_part = __half2float(esh);
    __half2 esp = __half2half2(esh);
    U16x8 hs;
    hs.u = *(const uint4*)(h1 + (size_t)wid * 128 + r * 8);
    __half2 a0 = __hmul2(hs.h[0], esp), a1 = __hmul2(hs.h[1], esp),
            a2 = __hmul2(hs.h[2], esp), a3 = __hmul2(hs.h[3], esp);
    if (nb > 0) {
        // pipelined ELL walk: lanes>=nb carry e=0, so no in-loop guard needed
        int src = __shfl(sv, g);
        int wpi = __shfl(we, g);
        U16x8 hc;
        hc.u = *(const uint4*)(h1 + (size_t)src * 128 + r * 8);
        __half wc = (r < 8) ? __low2half(i2h(wpi)) : __high2half(i2h(wpi));
        for (int j = 4; j < nb; j += 4) {
            int ej = j + g;
            int src2 = __shfl(sv, ej);
            int wpi2 = __shfl(we, ej);
            U16x8 hn;
            hn.u = *(const uint4*)(h1 + (size_t)src2 * 128 + r * 8);
            __half2 ww = __half2half2(wc);
            s_part += __half2float(wc);
            a0 = __hfma2(ww, hc.h[0], a0);
            a1 = __hfma2(ww, hc.h[1], a1);
            a2 = __hfma2(ww, hc.h[2], a2);
            a3 = __hfma2(ww, hc.h[3], a3);
            hc = hn;
            wc = (r < 8) ? __low2half(i2h(wpi2)) : __high2half(i2h(wpi2));
        }
        __half2 ww = __half2half2(wc);
        s_part += __half2float(wc);
        a0 = __hfma2(ww, hc.h[0], a0);
        a1 = __hfma2(ww, hc.h[1], a1);
        a2 = __hfma2(ww, hc.h[2], a2);
        a3 = __hfma2(ww, hc.h[3], a3);
    }
    // cross-group reduce (packed)
#pragma unroll
    for (int o = 16; o < 64; o <<= 1) {
        s_part += __shfl_xor(s_part, o);
        a0 = __hadd2(a0, i2h(__shfl_xor(h2i(a0), o)));
        a1 = __hadd2(a1, i2h(__shfl_xor(h2i(a1), o)));
        a2 = __hadd2(a2, i2h(__shfl_xor(h2i(a2), o)));
        a3 = __hadd2(a3, i2h(__shfl_xor(h2i(a3), o)));
    }
    if (g == 0) {
        float inv = 1.f / (s_part + 1e-16f);
        float4 bA = b1v[2 * r], bB = b1v[2 * r + 1];
        float v[8] = {__low2float(a0), __high2float(a0), __low2float(a1), __high2float(a1),
                      __low2float(a2), __high2float(a2), __low2float(a3), __high2float(a3)};
        float vb[8] = {bA.x, bA.y, bA.z, bA.w, bB.x, bB.y, bB.z, bB.w};
        U16x8 o;
#pragma unroll
        for (int k = 0; k < 8; k += 2) {
            float u0 = fmaf(v[k], inv, vb[k]);
            float u1 = fmaf(v[k + 1], inv, vb[k + 1]);
            u0 = (u0 > 0.f) ? u0 : (__expf(u0) - 1.f);  // ELU
            u1 = (u1 > 0.f) ? u1 : (__expf(u1) - 1.f);
            o.h[k >> 1] = __floats2half2_rn(u0, u1);
        }
        *(uint4*)(hf + (size_t)wid * 128 + r * 8) = o.u;
    }
}

// ---------------- fused gather layer 2: packed-fp16 math ----------------
// lane r<10 owns channels 4r..4r+3 (8B)
__global__ __launch_bounds__(256) void k_gather2(
    const int* __restrict__ cnt, const int* __restrict__ colell,
    const _Float16* __restrict__ h2, const float* __restrict__ alsrc,
    const float* __restrict__ aldst, const float4* __restrict__ b2v,
    float4* __restrict__ out4, int N) {
    int wid = (int)(((size_t)blockIdx.x * blockDim.x + threadIdx.x) >> 6);
    int lane = threadIdx.x & 63;
    if (wid >= N) return;
    int g = lane >> 4, r = lane & 15;
    int rc = (r < 10) ? r : 0;  // address clamp; lanes r>=10 compute junk, never written
    float ad = aldst[wid];
    float ls = lrelu(alsrc[wid] + ad);
    int nb = min(cnt[wid], 64);
    int sv = 0;
    float l = -1e30f;
    if (lane < nb) {
        sv = colell[(size_t)wid * 64 + lane];
        l = lrelu(alsrc[sv] + ad);
    }
    float m = l;
#pragma unroll
    for (int o = 32; o > 0; o >>= 1) m = fmaxf(m, __shfl_xor(m, o));
    m = fmaxf(m, ls);
    float e = (lane < nb) ? __expf(l - m) : 0.f;
    // self seed
    float es = (g == 0) ? __expf(ls - m) : 0.f;
    float s_part = es;
    __half2 esp = __floats2half2_rn(es, es);
    U16x4 hs;
    hs.u = *(const uint2*)(h2 + (size_t)wid * 40 + rc * 4);
    __half2 a0 = __hmul2(hs.h[0], esp), a1 = __hmul2(hs.h[1], esp);
    if (nb > 0) {
        int src = __shfl(sv, g);
        float wv = __shfl(e, g);
        U16x4 hc;
        hc.u = *(const uint2*)(h2 + (size_t)src * 40 + rc * 4);
        for (int j = 4; j < nb; j += 4) {
            int ej = j + g;
            int src2 = __shfl(sv, ej);
            float wv2 = __shfl(e, ej);
            U16x4 hn;
            hn.u = *(const uint2*)(h2 + (size_t)src2 * 40 + rc * 4);
            __half2 ww = __floats2half2_rn(wv, wv);
            s_part += wv;
            a0 = __hfma2(ww, hc.h[0], a0);
            a1 = __hfma2(ww, hc.h[1], a1);
            hc = hn;
            wv = wv2;
        }
        __half2 ww = __floats2half2_rn(wv, wv);
        s_part += wv;
        a0 = __hfma2(ww, hc.h[0], a0);
        a1 = __hfma2(ww, hc.h[1], a1);
    }
#pragma unroll
    for (int o = 16; o < 64; o <<= 1) {
        s_part += __shfl_xor(s_part, o);
        a0 = __hadd2(a0, i2h(__shfl_xor(h2i(a0), o)));
        a1 = __hadd2(a1, i2h(__shfl_xor(h2i(a1), o)));
    }
    if (g == 0 && r < 10) {
        float inv = 1.f / (s_part + 1e-16f);
        float4 b = b2v[r];
        float4 o = make_float4(fmaf(__low2float(a0), inv, b.x),
                               fmaf(__high2float(a0), inv, b.y),
                               fmaf(__low2float(a1), inv, b.z),
                               fmaf(__high2float(a1), inv, b.w));
        out4[(size_t)wid * 10 + r] = o;
    }
}

extern "C" void kernel_launch(void* const* d_in, const int* in_sizes, int n_in,
                              void* d_out, int out_size, void* d_ws, size_t ws_size,
                              hipStream_t stream) {
    const float* x   = (const float*)d_in[0];
    const int*   ei  = (const int*)d_in[1];
    const float* W1  = (const float*)d_in[2];
    const float* as1 = (const float*)d_in[3];
    const float* ad1 = (const float*)d_in[4];
    const float* b1  = (const float*)d_in[5];
    const float* W2  = (const float*)d_in[6];
    const float* as2 = (const float*)d_in[7];
    const float* ad2 = (const float*)d_in[8];
    const float* b2  = (const float*)d_in[9];
    int N = in_sizes[0] / 128;
    int E = in_sizes[1] / 2;
    float4* out4 = (float4*)d_out;

    char* ws = (char*)d_ws;
    size_t off = 0;
    auto alloc = [&](size_t bytes) {
        char* p = ws + off;
        off += (bytes + 255) & ~(size_t)255;
        return p;
    };
    int*      cnt    = (int*)alloc((size_t)N * 4);       // zero-init
    int*      colell = (int*)alloc((size_t)N * 64 * 4);  // ELL, stride 64
    _Float16* bp1    = (_Float16*)alloc(16384 * 2);
    _Float16* bp2    = (_Float16*)alloc(6144 * 2);
    _Float16* h1h    = (_Float16*)alloc((size_t)N * 128 * 2);  // fp16 [N][128]
    _Float16* hf     = (_Float16*)alloc((size_t)N * 128 * 2);  // fp16 [N][128]
    _Float16* h2h    = (_Float16*)alloc((size_t)N * 40 * 2);   // fp16 [N][40]
    float*    alsrc1 = (float*)alloc((size_t)N * 2 * 4);
    float*    aldst1 = (float*)alloc((size_t)N * 2 * 4);
    float*    alsrc2 = (float*)alloc((size_t)N * 4);
    float*    aldst2 = (float*)alloc((size_t)N * 4);

    (void)hipMemsetAsync(cnt, 0, (size_t)N * 4, stream);

    dim3 b256(256);
    int ps = (N + 7) / 8;
    int gB = 8 * ((E + 255) / 256);

    k_pack<<<(16384 + 6144 + 255) / 256, b256, 0, stream>>>(W1, W2, bp1, bp2);
    k_bucket<<<gB, b256, 0, stream>>>(ei, cnt, colell, E, ps);

    int gG = (N + 63) / 64;
    // layer 1
    k_gemm1<<<gG, b256, 0, stream>>>(x, bp1, as1, ad1, (__half2*)h1h, alsrc1, aldst1, N);
    k_gather1<<<(int)(((size_t)N * 64 + 255) / 256), b256, 0, stream>>>(
        cnt, colell, h1h, (const float2*)alsrc1, (const float2*)aldst1,
        (const float4*)b1, hf, N);

    // layer 2
    k_gemm2<<<gG, b256, 0, stream>>>(hf, bp2, as2, ad2, (__half2*)h2h, alsrc2, aldst2, N);
    k_gather2<<<(int)(((size_t)N * 64 + 255) / 256), b256, 0, stream>>>(
        cnt, colell, h2h, alsrc2, aldst2, (const float4*)b2, out4, N);
}

// Round 10
// 132.008 us; speedup vs baseline: 2.6355x; 1.0158x over previous
//
#include <hip/hip_runtime.h>
#include <hip/hip_fp16.h>

#define NEG_SLOPE 0.2f

typedef _Float16 f16x8 __attribute__((ext_vector_type(8)));
typedef float f32x4 __attribute__((ext_vector_type(4)));

__device__ __forceinline__ int h2i(__half2 h) { return *(int*)&h; }
__device__ __forceinline__ __half2 i2h(int i) { return *(__half2*)&i; }
__device__ __forceinline__ float lrelu(float v) { return (v > 0.f) ? v : NEG_SLOPE * v; }
__device__ __forceinline__ int pkmax(int a, int b) {
    int r;
    asm("v_pk_max_f16 %0, %1, %2" : "=v"(r) : "v"(a), "v"(b));
    return r;
}

union U16x8 { uint4 u; __half2 h[4]; };
union U16x4 { uint2 u; __half2 h[2]; };

// ---------------- pack W1/W2 into MFMA B-fragment order + zero cnt ----------
__global__ __launch_bounds__(256) void k_pack(const float* __restrict__ W1,
                                              const float* __restrict__ W2,
                                              _Float16* __restrict__ bp1,
                                              _Float16* __restrict__ bp2,
                                              int* __restrict__ cnt, int N) {
    int idx = blockIdx.x * 256 + threadIdx.x;
    if (idx < N) cnt[idx] = 0;  // replaces the 43us rocclr fillBuffer
    if (idx < 16384) {  // W1: 4 ks * 8 nt * 64 * 8
        int j = idx & 7, l = (idx >> 3) & 63, nt = (idx >> 9) & 7, ks = idx >> 12;
        int k = ks * 32 + (l >> 4) * 8 + j;
        int col = nt * 16 + (l & 15);
        bp1[idx] = (_Float16)W1[k * 128 + col];
    }
    int idx2 = idx - 16384;
    if (idx2 >= 0 && idx2 < 6144) {  // W2: 4 ks * 3 nt * 64 * 8 (cols >=40 zero)
        int j = idx2 & 7, l = (idx2 >> 3) & 63, q = idx2 >> 9;
        int nt = q % 3, ks = q / 3;
        int k = ks * 32 + (l >> 4) * 8 + j;
        int col = nt * 16 + (l & 15);
        bp2[idx2] = (col < 40) ? (_Float16)W2[k * 40 + col] : (_Float16)0.f;
    }
}

// ---------------- one-pass ELL bucket build ----------------
__global__ void k_bucket(const int* __restrict__ ei, int* __restrict__ cnt,
                         int* __restrict__ colell, int E, int ps) {
    int p = blockIdx.x & 7;
    int e = (blockIdx.x >> 3) * blockDim.x + threadIdx.x;
    if (e >= E) return;
    int d = ei[E + e];
    int lo = p * ps;
    if (d < lo || d >= lo + ps) return;
    int s = ei[e];
    int rank = atomicAdd(&cnt[d], 1);
    if (rank < 64) colell[(size_t)d * 64 + rank] = s;
}

// ---------------- GEMM1 (MFMA): h1 = x @ W1 + attention logits ----------------
__global__ __launch_bounds__(256) void k_gemm1(
    const float* __restrict__ x, const _Float16* __restrict__ bp1,
    const float* __restrict__ as1, const float* __restrict__ ad1,
    __half2* __restrict__ h1h, float* __restrict__ alsrc, float* __restrict__ aldst,
    int N) {
    int w = threadIdx.x >> 6, l = threadIdx.x & 63;
    int n0 = blockIdx.x * 64 + w * 16;
    int li = l & 15, lg = l >> 4;
    int arow = n0 + li;
    f16x8 a[4];
#pragma unroll
    for (int ks = 0; ks < 4; ks++) {
        float4 p0 = make_float4(0, 0, 0, 0), p1 = make_float4(0, 0, 0, 0);
        if (arow < N) {
            const float4* src = (const float4*)(x + (size_t)arow * 128 + ks * 32 + lg * 8);
            p0 = src[0];
            p1 = src[1];
        }
        f16x8 t;
        t[0] = (_Float16)p0.x; t[1] = (_Float16)p0.y; t[2] = (_Float16)p0.z; t[3] = (_Float16)p0.w;
        t[4] = (_Float16)p1.x; t[5] = (_Float16)p1.y; t[6] = (_Float16)p1.z; t[7] = (_Float16)p1.w;
        a[ks] = t;
    }
    f32x4 acc[8];
#pragma unroll
    for (int nt = 0; nt < 8; nt++) acc[nt] = (f32x4){0.f, 0.f, 0.f, 0.f};
    const f16x8* bp = (const f16x8*)bp1;
#pragma unroll
    for (int nt = 0; nt < 8; nt++)
#pragma unroll
        for (int ks = 0; ks < 4; ks++)
            acc[nt] = __builtin_amdgcn_mfma_f32_16x16x32_f16(a[ks], bp[(ks * 8 + nt) * 64 + l],
                                                             acc[nt], 0, 0, 0);
    float as1v[8], ad1v[8];
#pragma unroll
    for (int nt = 0; nt < 8; nt++) {
        as1v[nt] = as1[nt * 16 + li];
        ad1v[nt] = ad1[nt * 16 + li];
    }
#pragma unroll
    for (int r = 0; r < 4; r++) {
        float ps0 = 0, ps1 = 0, pd0 = 0, pd1 = 0;
#pragma unroll
        for (int nt = 0; nt < 4; nt++) {
            ps0 = fmaf(acc[nt][r], as1v[nt], ps0);
            pd0 = fmaf(acc[nt][r], ad1v[nt], pd0);
        }
#pragma unroll
        for (int nt = 4; nt < 8; nt++) {
            ps1 = fmaf(acc[nt][r], as1v[nt], ps1);
            pd1 = fmaf(acc[nt][r], ad1v[nt], pd1);
        }
#pragma unroll
        for (int o = 1; o < 16; o <<= 1) {
            ps0 += __shfl_xor(ps0, o);
            ps1 += __shfl_xor(ps1, o);
            pd0 += __shfl_xor(pd0, o);
            pd1 += __shfl_xor(pd1, o);
        }
        int node = n0 + lg * 4 + r;
        if (li == 0 && node < N) {
            alsrc[node * 2] = ps0;
            alsrc[node * 2 + 1] = ps1;
            aldst[node * 2] = pd0;
            aldst[node * 2 + 1] = pd1;
        }
    }
#pragma unroll
    for (int nt = 0; nt < 8; nt++)
#pragma unroll
        for (int r = 0; r < 4; r++) {
            float v = acc[nt][r];
            float p = __shfl_down(v, 1);
            int node = n0 + lg * 4 + r;
            if ((l & 1) == 0 && node < N)
                h1h[(size_t)node * 64 + nt * 8 + (li >> 1)] = __floats2half2_rn(v, p);
        }
}

// ---------------- GEMM2 (MFMA): h2 = hf(fp16) @ W2 + attention logits --------
__global__ __launch_bounds__(256) void k_gemm2(
    const _Float16* __restrict__ hf, const _Float16* __restrict__ bp2,
    const float* __restrict__ as2, const float* __restrict__ ad2,
    __half2* __restrict__ h2h, float* __restrict__ alsrc, float* __restrict__ aldst,
    int N) {
    int w = threadIdx.x >> 6, l = threadIdx.x & 63;
    int n0 = blockIdx.x * 64 + w * 16;
    int li = l & 15, lg = l >> 4;
    int arow = n0 + li;
    const f16x8* hfv = (const f16x8*)hf;
    f16x8 a[4];
#pragma unroll
    for (int ks = 0; ks < 4; ks++) {
        f16x8 t;
        if (arow < N) {
            t = hfv[(size_t)arow * 16 + ks * 4 + lg];
        } else {
#pragma unroll
            for (int k = 0; k < 8; k++) t[k] = (_Float16)0.f;
        }
        a[ks] = t;
    }
    f32x4 acc[3];
#pragma unroll
    for (int nt = 0; nt < 3; nt++) acc[nt] = (f32x4){0.f, 0.f, 0.f, 0.f};
    const f16x8* bp = (const f16x8*)bp2;
#pragma unroll
    for (int nt = 0; nt < 3; nt++)
#pragma unroll
        for (int ks = 0; ks < 4; ks++)
            acc[nt] = __builtin_amdgcn_mfma_f32_16x16x32_f16(a[ks], bp[(ks * 3 + nt) * 64 + l],
                                                             acc[nt], 0, 0, 0);
    float as2v[3], ad2v[3];
#pragma unroll
    for (int nt = 0; nt < 3; nt++) {
        int col = nt * 16 + li;
        as2v[nt] = (col < 40) ? as2[col] : 0.f;
        ad2v[nt] = (col < 40) ? ad2[col] : 0.f;
    }
#pragma unroll
    for (int r = 0; r < 4; r++) {
        float ps = 0, pd = 0;
#pragma unroll
        for (int nt = 0; nt < 3; nt++) {
            ps = fmaf(acc[nt][r], as2v[nt], ps);
            pd = fmaf(acc[nt][r], ad2v[nt], pd);
        }
#pragma unroll
        for (int o = 1; o < 16; o <<= 1) {
            ps += __shfl_xor(ps, o);
            pd += __shfl_xor(pd, o);
        }
        int node = n0 + lg * 4 + r;
        if (li == 0 && node < N) {
            alsrc[node] = ps;
            aldst[node] = pd;
        }
    }
#pragma unroll
    for (int nt = 0; nt < 3; nt++)
#pragma unroll
        for (int r = 0; r < 4; r++) {
            float v = acc[nt][r];
            float p = __shfl_down(v, 1);
            int node = n0 + lg * 4 + r;
            int col = nt * 16 + li;
            if ((l & 1) == 0 && col < 40 && node < N)
                h2h[(size_t)node * 20 + nt * 8 + (li >> 1)] = __floats2half2_rn(v, p);
        }
}

// ---------------- fused gather layer 1: packed-fp16 math ----------------
// group g=lane>>4 handles edges j+g; lane r=lane&15 owns channels 8r..8r+7
__global__ __launch_bounds__(256) void k_gather1(
    const int* __restrict__ cnt, const int* __restrict__ colell,
    const _Float16* __restrict__ h1, const float2* __restrict__ alsrc,
    const float2* __restrict__ aldst, const float4* __restrict__ b1v,
    _Float16* __restrict__ hf, int N) {
    int wid = (int)(((size_t)blockIdx.x * blockDim.x + threadIdx.x) >> 6);
    int lane = threadIdx.x & 63;
    if (wid >= N) return;
    int g = lane >> 4, r = lane & 15;
    float2 asn = alsrc[wid], ad = aldst[wid];
    float ls0 = lrelu(asn.x + ad.x);
    float ls1 = lrelu(asn.y + ad.y);
    int nb = min(cnt[wid], 64);
    // per-edge logits (lane = edge slot)
    int sv = 0;
    float l0 = -1e30f, l1 = -1e30f;
    if (lane < nb) {
        sv = colell[(size_t)wid * 64 + lane];
        float2 av = alsrc[sv];
        l0 = lrelu(av.x + ad.x);
        l1 = lrelu(av.y + ad.y);
    }
    // packed max reduce over 64 lanes (both heads at once)
    int lpi = h2i(__floats2half2_rn(l0, l1));
#pragma unroll
    for (int o = 32; o > 0; o >>= 1) lpi = pkmax(lpi, __shfl_xor(lpi, o));
    __half2 lp = i2h(lpi);
    float m0 = fmaxf(__low2float(lp), ls0);
    float m1 = fmaxf(__high2float(lp), ls1);
    float e0 = (lane < nb) ? __expf(l0 - m0) : 0.f;
    float e1 = (lane < nb) ? __expf(l1 - m1) : 0.f;
    int we = h2i(__floats2half2_rn(e0, e1));  // packed weights, one shfl for both heads
    // self-loop seed
    float lsh = (r < 8) ? ls0 : ls1;
    float mh = (r < 8) ? m0 : m1;
    __half esh = __float2half((g == 0) ? __expf(lsh - mh) : 0.f);
    float s_part = __half2float(esh);
    __half2 esp = __half2half2(esh);
    U16x8 hs;
    hs.u = *(const uint4*)(h1 + (size_t)wid * 128 + r * 8);
    __half2 a0 = __hmul2(hs.h[0], esp), a1 = __hmul2(hs.h[1], esp),
            a2 = __hmul2(hs.h[2], esp), a3 = __hmul2(hs.h[3], esp);
    if (nb > 0) {
        // pipelined ELL walk: lanes>=nb carry e=0, so no in-loop guard needed
        int src = __shfl(sv, g);
        int wpi = __shfl(we, g);
        U16x8 hc;
        hc.u = *(const uint4*)(h1 + (size_t)src * 128 + r * 8);
        __half wc = (r < 8) ? __low2half(i2h(wpi)) : __high2half(i2h(wpi));
        for (int j = 4; j < nb; j += 4) {
            int ej = j + g;
            int src2 = __shfl(sv, ej);
            int wpi2 = __shfl(we, ej);
            U16x8 hn;
            hn.u = *(const uint4*)(h1 + (size_t)src2 * 128 + r * 8);
            __half2 ww = __half2half2(wc);
            s_part += __half2float(wc);
            a0 = __hfma2(ww, hc.h[0], a0);
            a1 = __hfma2(ww, hc.h[1], a1);
            a2 = __hfma2(ww, hc.h[2], a2);
            a3 = __hfma2(ww, hc.h[3], a3);
            hc = hn;
            wc = (r < 8) ? __low2half(i2h(wpi2)) : __high2half(i2h(wpi2));
        }
        __half2 ww = __half2half2(wc);
        s_part += __half2float(wc);
        a0 = __hfma2(ww, hc.h[0], a0);
        a1 = __hfma2(ww, hc.h[1], a1);
        a2 = __hfma2(ww, hc.h[2], a2);
        a3 = __hfma2(ww, hc.h[3], a3);
    }
    // cross-group reduce (packed)
#pragma unroll
    for (int o = 16; o < 64; o <<= 1) {
        s_part += __shfl_xor(s_part, o);
        a0 = __hadd2(a0, i2h(__shfl_xor(h2i(a0), o)));
        a1 = __hadd2(a1, i2h(__shfl_xor(h2i(a1), o)));
        a2 = __hadd2(a2, i2h(__shfl_xor(h2i(a2), o)));
        a3 = __hadd2(a3, i2h(__shfl_xor(h2i(a3), o)));
    }
    if (g == 0) {
        float inv = 1.f / (s_part + 1e-16f);
        float4 bA = b1v[2 * r], bB = b1v[2 * r + 1];
        float v[8] = {__low2float(a0), __high2float(a0), __low2float(a1), __high2float(a1),
                      __low2float(a2), __high2float(a2), __low2float(a3), __high2float(a3)};
        float vb[8] = {bA.x, bA.y, bA.z, bA.w, bB.x, bB.y, bB.z, bB.w};
        U16x8 o;
#pragma unroll
        for (int k = 0; k < 8; k += 2) {
            float u0 = fmaf(v[k], inv, vb[k]);
            float u1 = fmaf(v[k + 1], inv, vb[k + 1]);
            u0 = (u0 > 0.f) ? u0 : (__expf(u0) - 1.f);  // ELU
            u1 = (u1 > 0.f) ? u1 : (__expf(u1) - 1.f);
            o.h[k >> 1] = __floats2half2_rn(u0, u1);
        }
        *(uint4*)(hf + (size_t)wid * 128 + r * 8) = o.u;
    }
}

// ---------------- fused gather layer 2: packed-fp16 math ----------------
// lane r<10 owns channels 4r..4r+3 (8B)
__global__ __launch_bounds__(256) void k_gather2(
    const int* __restrict__ cnt, const int* __restrict__ colell,
    const _Float16* __restrict__ h2, const float* __restrict__ alsrc,
    const float* __restrict__ aldst, const float4* __restrict__ b2v,
    float4* __restrict__ out4, int N) {
    int wid = (int)(((size_t)blockIdx.x * blockDim.x + threadIdx.x) >> 6);
    int lane = threadIdx.x & 63;
    if (wid >= N) return;
    int g = lane >> 4, r = lane & 15;
    int rc = (r < 10) ? r : 0;  // address clamp; lanes r>=10 compute junk, never written
    float ad = aldst[wid];
    float ls = lrelu(alsrc[wid] + ad);
    int nb = min(cnt[wid], 64);
    int sv = 0;
    float l = -1e30f;
    if (lane < nb) {
        sv = colell[(size_t)wid * 64 + lane];
        l = lrelu(alsrc[sv] + ad);
    }
    float m = l;
#pragma unroll
    for (int o = 32; o > 0; o >>= 1) m = fmaxf(m, __shfl_xor(m, o));
    m = fmaxf(m, ls);
    float e = (lane < nb) ? __expf(l - m) : 0.f;
    // self seed
    float es = (g == 0) ? __expf(ls - m) : 0.f;
    float s_part = es;
    __half2 esp = __floats2half2_rn(es, es);
    U16x4 hs;
    hs.u = *(const uint2*)(h2 + (size_t)wid * 40 + rc * 4);
    __half2 a0 = __hmul2(hs.h[0], esp), a1 = __hmul2(hs.h[1], esp);
    if (nb > 0) {
        int src = __shfl(sv, g);
        float wv = __shfl(e, g);
        U16x4 hc;
        hc.u = *(const uint2*)(h2 + (size_t)src * 40 + rc * 4);
        for (int j = 4; j < nb; j += 4) {
            int ej = j + g;
            int src2 = __shfl(sv, ej);
            float wv2 = __shfl(e, ej);
            U16x4 hn;
            hn.u = *(const uint2*)(h2 + (size_t)src2 * 40 + rc * 4);
            __half2 ww = __floats2half2_rn(wv, wv);
            s_part += wv;
            a0 = __hfma2(ww, hc.h[0], a0);
            a1 = __hfma2(ww, hc.h[1], a1);
            hc = hn;
            wv = wv2;
        }
        __half2 ww = __floats2half2_rn(wv, wv);
        s_part += wv;
        a0 = __hfma2(ww, hc.h[0], a0);
        a1 = __hfma2(ww, hc.h[1], a1);
    }
#pragma unroll
    for (int o = 16; o < 64; o <<= 1) {
        s_part += __shfl_xor(s_part, o);
        a0 = __hadd2(a0, i2h(__shfl_xor(h2i(a0), o)));
        a1 = __hadd2(a1, i2h(__shfl_xor(h2i(a1), o)));
    }
    if (g == 0 && r < 10) {
        float inv = 1.f / (s_part + 1e-16f);
        float4 b = b2v[r];
        float4 o = make_float4(fmaf(__low2float(a0), inv, b.x),
                               fmaf(__high2float(a0), inv, b.y),
                               fmaf(__low2float(a1), inv, b.z),
                               fmaf(__high2float(a1), inv, b.w));
        out4[(size_t)wid * 10 + r] = o;
    }
}

extern "C" void kernel_launch(void* const* d_in, const int* in_sizes, int n_in,
                              void* d_out, int out_size, void* d_ws, size_t ws_size,
                              hipStream_t stream) {
    const float* x   = (const float*)d_in[0];
    const int*   ei  = (const int*)d_in[1];
    const float* W1  = (const float*)d_in[2];
    const float* as1 = (const float*)d_in[3];
    const float* ad1 = (const float*)d_in[4];
    const float* b1  = (const float*)d_in[5];
    const float* W2  = (const float*)d_in[6];
    const float* as2 = (const float*)d_in[7];
    const float* ad2 = (const float*)d_in[8];
    const float* b2  = (const float*)d_in[9];
    int N = in_sizes[0] / 128;
    int E = in_sizes[1] / 2;
    float4* out4 = (float4*)d_out;

    char* ws = (char*)d_ws;
    size_t off = 0;
    auto alloc = [&](size_t bytes) {
        char* p = ws + off;
        off += (bytes + 255) & ~(size_t)255;
        return p;
    };
    int*      cnt    = (int*)alloc((size_t)N * 4);       // zeroed in k_pack
    int*      colell = (int*)alloc((size_t)N * 64 * 4);  // ELL, stride 64
    _Float16* bp1    = (_Float16*)alloc(16384 * 2);
    _Float16* bp2    = (_Float16*)alloc(6144 * 2);
    _Float16* h1h    = (_Float16*)alloc((size_t)N * 128 * 2);  // fp16 [N][128]
    _Float16* hf     = (_Float16*)alloc((size_t)N * 128 * 2);  // fp16 [N][128]
    _Float16* h2h    = (_Float16*)alloc((size_t)N * 40 * 2);   // fp16 [N][40]
    float*    alsrc1 = (float*)alloc((size_t)N * 2 * 4);
    float*    aldst1 = (float*)alloc((size_t)N * 2 * 4);
    float*    alsrc2 = (float*)alloc((size_t)N * 4);
    float*    aldst2 = (float*)alloc((size_t)N * 4);

    dim3 b256(256);
    int ps = (N + 7) / 8;
    int gB = 8 * ((E + 255) / 256);
    int gP = (N > 22528 ? N + 255 : 22528 + 255) / 256;  // covers packing AND cnt zeroing

    k_pack<<<gP, b256, 0, stream>>>(W1, W2, bp1, bp2, cnt, N);
    k_bucket<<<gB, b256, 0, stream>>>(ei, cnt, colell, E, ps);

    int gG = (N + 63) / 64;
    // layer 1
    k_gemm1<<<gG, b256, 0, stream>>>(x, bp1, as1, ad1, (__half2*)h1h, alsrc1, aldst1, N);
    k_gather1<<<(int)(((size_t)N * 64 + 255) / 256), b256, 0, stream>>>(
        cnt, colell, h1h, (const float2*)alsrc1, (const float2*)aldst1,
        (const float4*)b1, hf, N);

    // layer 2
    k_gemm2<<<gG, b256, 0, stream>>>(hf, bp2, as2, ad2, (__half2*)h2h, alsrc2, aldst2, N);
    k_gather2<<<(int)(((size_t)N * 64 + 255) / 256), b256, 0, stream>>>(
        cnt, colell, h2h, alsrc2, aldst2, (const float4*)b2, out4, N);
}

// Round 11
// 125.971 us; speedup vs baseline: 2.7618x; 1.0479x over previous
//
#include <hip/hip_runtime.h>
#include <hip/hip_fp16.h>

#define NEG_SLOPE 0.2f

typedef _Float16 f16x8 __attribute__((ext_vector_type(8)));
typedef float f32x4 __attribute__((ext_vector_type(4)));

__device__ __forceinline__ int h2i(__half2 h) { return *(int*)&h; }
__device__ __forceinline__ __half2 i2h(int i) { return *(__half2*)&i; }
__device__ __forceinline__ float lrelu(float v) { return (v > 0.f) ? v : NEG_SLOPE * v; }
__device__ __forceinline__ int pkmax(int a, int b) {
    int r;
    asm("v_pk_max_f16 %0, %1, %2" : "=v"(r) : "v"(a), "v"(b));
    return r;
}
__device__ __forceinline__ __half selh(int r, int packed) {
    return (r < 8) ? __low2half(i2h(packed)) : __high2half(i2h(packed));
}

union U16x8 { uint4 u; __half2 h[4]; };
union U16x4 { uint2 u; __half2 h[2]; };

// ---------------- pack W1/W2 into MFMA B-fragment order + zero cnt ----------
__global__ __launch_bounds__(256) void k_pack(const float* __restrict__ W1,
                                              const float* __restrict__ W2,
                                              _Float16* __restrict__ bp1,
                                              _Float16* __restrict__ bp2,
                                              int* __restrict__ cnt, int N) {
    int idx = blockIdx.x * 256 + threadIdx.x;
    if (idx < N) cnt[idx] = 0;
    if (idx < 16384) {  // W1: 4 ks * 8 nt * 64 * 8
        int j = idx & 7, l = (idx >> 3) & 63, nt = (idx >> 9) & 7, ks = idx >> 12;
        int k = ks * 32 + (l >> 4) * 8 + j;
        int col = nt * 16 + (l & 15);
        bp1[idx] = (_Float16)W1[k * 128 + col];
    }
    int idx2 = idx - 16384;
    if (idx2 >= 0 && idx2 < 6144) {  // W2: 4 ks * 3 nt * 64 * 8 (cols >=40 zero)
        int j = idx2 & 7, l = (idx2 >> 3) & 63, q = idx2 >> 9;
        int nt = q % 3, ks = q / 3;
        int k = ks * 32 + (l >> 4) * 8 + j;
        int col = nt * 16 + (l & 15);
        bp2[idx2] = (col < 40) ? (_Float16)W2[k * 40 + col] : (_Float16)0.f;
    }
}

// ---------------- one-pass ELL bucket build ----------------
__global__ void k_bucket(const int* __restrict__ ei, int* __restrict__ cnt,
                         int* __restrict__ colell, int E, int ps) {
    int p = blockIdx.x & 7;
    int e = (blockIdx.x >> 3) * blockDim.x + threadIdx.x;
    if (e >= E) return;
    int d = ei[E + e];
    int lo = p * ps;
    if (d < lo || d >= lo + ps) return;
    int s = ei[e];
    int rank = atomicAdd(&cnt[d], 1);
    if (rank < 64) colell[(size_t)d * 64 + rank] = s;
}

// ---------------- GEMM1 (MFMA): h1 = x @ W1 + attention logits ----------------
__global__ __launch_bounds__(256) void k_gemm1(
    const float* __restrict__ x, const _Float16* __restrict__ bp1,
    const float* __restrict__ as1, const float* __restrict__ ad1,
    __half2* __restrict__ h1h, float* __restrict__ alsrc, float* __restrict__ aldst,
    int N) {
    int w = threadIdx.x >> 6, l = threadIdx.x & 63;
    int n0 = blockIdx.x * 64 + w * 16;
    int li = l & 15, lg = l >> 4;
    int arow = n0 + li;
    f16x8 a[4];
#pragma unroll
    for (int ks = 0; ks < 4; ks++) {
        float4 p0 = make_float4(0, 0, 0, 0), p1 = make_float4(0, 0, 0, 0);
        if (arow < N) {
            const float4* src = (const float4*)(x + (size_t)arow * 128 + ks * 32 + lg * 8);
            p0 = src[0];
            p1 = src[1];
        }
        f16x8 t;
        t[0] = (_Float16)p0.x; t[1] = (_Float16)p0.y; t[2] = (_Float16)p0.z; t[3] = (_Float16)p0.w;
        t[4] = (_Float16)p1.x; t[5] = (_Float16)p1.y; t[6] = (_Float16)p1.z; t[7] = (_Float16)p1.w;
        a[ks] = t;
    }
    f32x4 acc[8];
#pragma unroll
    for (int nt = 0; nt < 8; nt++) acc[nt] = (f32x4){0.f, 0.f, 0.f, 0.f};
    const f16x8* bp = (const f16x8*)bp1;
#pragma unroll
    for (int nt = 0; nt < 8; nt++)
#pragma unroll
        for (int ks = 0; ks < 4; ks++)
            acc[nt] = __builtin_amdgcn_mfma_f32_16x16x32_f16(a[ks], bp[(ks * 8 + nt) * 64 + l],
                                                             acc[nt], 0, 0, 0);
    float as1v[8], ad1v[8];
#pragma unroll
    for (int nt = 0; nt < 8; nt++) {
        as1v[nt] = as1[nt * 16 + li];
        ad1v[nt] = ad1[nt * 16 + li];
    }
#pragma unroll
    for (int r = 0; r < 4; r++) {
        float ps0 = 0, ps1 = 0, pd0 = 0, pd1 = 0;
#pragma unroll
        for (int nt = 0; nt < 4; nt++) {
            ps0 = fmaf(acc[nt][r], as1v[nt], ps0);
            pd0 = fmaf(acc[nt][r], ad1v[nt], pd0);
        }
#pragma unroll
        for (int nt = 4; nt < 8; nt++) {
            ps1 = fmaf(acc[nt][r], as1v[nt], ps1);
            pd1 = fmaf(acc[nt][r], ad1v[nt], pd1);
        }
#pragma unroll
        for (int o = 1; o < 16; o <<= 1) {
            ps0 += __shfl_xor(ps0, o);
            ps1 += __shfl_xor(ps1, o);
            pd0 += __shfl_xor(pd0, o);
            pd1 += __shfl_xor(pd1, o);
        }
        int node = n0 + lg * 4 + r;
        if (li == 0 && node < N) {
            alsrc[node * 2] = ps0;
            alsrc[node * 2 + 1] = ps1;
            aldst[node * 2] = pd0;
            aldst[node * 2 + 1] = pd1;
        }
    }
#pragma unroll
    for (int nt = 0; nt < 8; nt++)
#pragma unroll
        for (int r = 0; r < 4; r++) {
            float v = acc[nt][r];
            float p = __shfl_down(v, 1);
            int node = n0 + lg * 4 + r;
            if ((l & 1) == 0 && node < N)
                h1h[(size_t)node * 64 + nt * 8 + (li >> 1)] = __floats2half2_rn(v, p);
        }
}

// ---------------- GEMM2 (MFMA): h2 = hf(fp16) @ W2 + attention logits --------
__global__ __launch_bounds__(256) void k_gemm2(
    const _Float16* __restrict__ hf, const _Float16* __restrict__ bp2,
    const float* __restrict__ as2, const float* __restrict__ ad2,
    __half2* __restrict__ h2h, float* __restrict__ alsrc, float* __restrict__ aldst,
    int N) {
    int w = threadIdx.x >> 6, l = threadIdx.x & 63;
    int n0 = blockIdx.x * 64 + w * 16;
    int li = l & 15, lg = l >> 4;
    int arow = n0 + li;
    const f16x8* hfv = (const f16x8*)hf;
    f16x8 a[4];
#pragma unroll
    for (int ks = 0; ks < 4; ks++) {
        f16x8 t;
        if (arow < N) {
            t = hfv[(size_t)arow * 16 + ks * 4 + lg];
        } else {
#pragma unroll
            for (int k = 0; k < 8; k++) t[k] = (_Float16)0.f;
        }
        a[ks] = t;
    }
    f32x4 acc[3];
#pragma unroll
    for (int nt = 0; nt < 3; nt++) acc[nt] = (f32x4){0.f, 0.f, 0.f, 0.f};
    const f16x8* bp = (const f16x8*)bp2;
#pragma unroll
    for (int nt = 0; nt < 3; nt++)
#pragma unroll
        for (int ks = 0; ks < 4; ks++)
            acc[nt] = __builtin_amdgcn_mfma_f32_16x16x32_f16(a[ks], bp[(ks * 3 + nt) * 64 + l],
                                                             acc[nt], 0, 0, 0);
    float as2v[3], ad2v[3];
#pragma unroll
    for (int nt = 0; nt < 3; nt++) {
        int col = nt * 16 + li;
        as2v[nt] = (col < 40) ? as2[col] : 0.f;
        ad2v[nt] = (col < 40) ? ad2[col] : 0.f;
    }
#pragma unroll
    for (int r = 0; r < 4; r++) {
        float ps = 0, pd = 0;
#pragma unroll
        for (int nt = 0; nt < 3; nt++) {
            ps = fmaf(acc[nt][r], as2v[nt], ps);
            pd = fmaf(acc[nt][r], ad2v[nt], pd);
        }
#pragma unroll
        for (int o = 1; o < 16; o <<= 1) {
            ps += __shfl_xor(ps, o);
            pd += __shfl_xor(pd, o);
        }
        int node = n0 + lg * 4 + r;
        if (li == 0 && node < N) {
            alsrc[node] = ps;
            aldst[node] = pd;
        }
    }
#pragma unroll
    for (int nt = 0; nt < 3; nt++)
#pragma unroll
        for (int r = 0; r < 4; r++) {
            float v = acc[nt][r];
            float p = __shfl_down(v, 1);
            int node = n0 + lg * 4 + r;
            int col = nt * 16 + li;
            if ((l & 1) == 0 && col < 40 && node < N)
                h2h[(size_t)node * 20 + nt * 8 + (li >> 1)] = __floats2half2_rn(v, p);
        }
}

// ---------------- fused gather layer 1: packed-fp16 + 4-deep load pipeline ----
// group g=lane>>4 handles edges j+g; lane r=lane&15 owns channels 8r..8r+7.
// Out-of-range edge slots carry e=0 / sv=0 -> loads are guard-free and safe.
__global__ __launch_bounds__(256) void k_gather1(
    const int* __restrict__ cnt, const int* __restrict__ colell,
    const _Float16* __restrict__ h1, const float2* __restrict__ alsrc,
    const float2* __restrict__ aldst, const float4* __restrict__ b1v,
    _Float16* __restrict__ hf, int N) {
    int wid = (int)(((size_t)blockIdx.x * blockDim.x + threadIdx.x) >> 6);
    int lane = threadIdx.x & 63;
    if (wid >= N) return;
    int g = lane >> 4, r = lane & 15;
    float2 asn = alsrc[wid], ad = aldst[wid];
    float ls0 = lrelu(asn.x + ad.x);
    float ls1 = lrelu(asn.y + ad.y);
    int nb = min(cnt[wid], 64);
    int sv = 0;
    float l0 = -1e30f, l1 = -1e30f;
    if (lane < nb) {
        sv = colell[(size_t)wid * 64 + lane];
        float2 av = alsrc[sv];
        l0 = lrelu(av.x + ad.x);
        l1 = lrelu(av.y + ad.y);
    }
    int lpi = h2i(__floats2half2_rn(l0, l1));
#pragma unroll
    for (int o = 32; o > 0; o >>= 1) lpi = pkmax(lpi, __shfl_xor(lpi, o));
    __half2 lp = i2h(lpi);
    float m0 = fmaxf(__low2float(lp), ls0);
    float m1 = fmaxf(__high2float(lp), ls1);
    float e0 = (lane < nb) ? __expf(l0 - m0) : 0.f;
    float e1 = (lane < nb) ? __expf(l1 - m1) : 0.f;
    int we = h2i(__floats2half2_rn(e0, e1));
    // self-loop seed
    float lsh = (r < 8) ? ls0 : ls1;
    float mh = (r < 8) ? m0 : m1;
    __half esh = __float2half((g == 0) ? __expf(lsh - mh) : 0.f);
    float s_part = __half2float(esh);
    __half2 esp = __half2half2(esh);
    U16x8 hs;
    hs.u = *(const uint4*)(h1 + (size_t)wid * 128 + r * 8);
    __half2 a0 = __hmul2(hs.h[0], esp), a1 = __hmul2(hs.h[1], esp),
            a2 = __hmul2(hs.h[2], esp), a3 = __hmul2(hs.h[3], esp);
    if (nb > 0) {
        // 4-deep rolling pipeline: loads for edge slots 0..15 in flight before
        // first consume; slots >= nb have zero weight (no guards needed).
        int i0 = __shfl(sv, g),      p0 = __shfl(we, g);
        int i1 = __shfl(sv, 4 + g),  p1 = __shfl(we, 4 + g);
        int i2 = __shfl(sv, 8 + g),  p2 = __shfl(we, 8 + g);
        int i3 = __shfl(sv, 12 + g), p3 = __shfl(we, 12 + g);
        U16x8 hA, hB, hC, hD;
        hA.u = *(const uint4*)(h1 + (size_t)i0 * 128 + r * 8);
        hB.u = *(const uint4*)(h1 + (size_t)i1 * 128 + r * 8);
        hC.u = *(const uint4*)(h1 + (size_t)i2 * 128 + r * 8);
        hD.u = *(const uint4*)(h1 + (size_t)i3 * 128 + r * 8);
        __half wA = selh(r, p0), wB = selh(r, p1), wC = selh(r, p2), wD = selh(r, p3);
        for (int j = 16; j < nb; j += 4) {
            int i4 = __shfl(sv, j + g), p4 = __shfl(we, j + g);
            U16x8 hN;
            hN.u = *(const uint4*)(h1 + (size_t)i4 * 128 + r * 8);
            __half2 ww = __half2half2(wA);
            s_part += __half2float(wA);
            a0 = __hfma2(ww, hA.h[0], a0);
            a1 = __hfma2(ww, hA.h[1], a1);
            a2 = __hfma2(ww, hA.h[2], a2);
            a3 = __hfma2(ww, hA.h[3], a3);
            hA = hB; wA = wB;
            hB = hC; wB = wC;
            hC = hD; wC = wD;
            hD = hN; wD = selh(r, p4);
        }
        // epilogue: consume the 4 in-flight groups
        {
            __half2 ww = __half2half2(wA);
            s_part += __half2float(wA);
            a0 = __hfma2(ww, hA.h[0], a0); a1 = __hfma2(ww, hA.h[1], a1);
            a2 = __hfma2(ww, hA.h[2], a2); a3 = __hfma2(ww, hA.h[3], a3);
        }
        {
            __half2 ww = __half2half2(wB);
            s_part += __half2float(wB);
            a0 = __hfma2(ww, hB.h[0], a0); a1 = __hfma2(ww, hB.h[1], a1);
            a2 = __hfma2(ww, hB.h[2], a2); a3 = __hfma2(ww, hB.h[3], a3);
        }
        {
            __half2 ww = __half2half2(wC);
            s_part += __half2float(wC);
            a0 = __hfma2(ww, hC.h[0], a0); a1 = __hfma2(ww, hC.h[1], a1);
            a2 = __hfma2(ww, hC.h[2], a2); a3 = __hfma2(ww, hC.h[3], a3);
        }
        {
            __half2 ww = __half2half2(wD);
            s_part += __half2float(wD);
            a0 = __hfma2(ww, hD.h[0], a0); a1 = __hfma2(ww, hD.h[1], a1);
            a2 = __hfma2(ww, hD.h[2], a2); a3 = __hfma2(ww, hD.h[3], a3);
        }
    }
    // cross-group reduce (packed)
#pragma unroll
    for (int o = 16; o < 64; o <<= 1) {
        s_part += __shfl_xor(s_part, o);
        a0 = __hadd2(a0, i2h(__shfl_xor(h2i(a0), o)));
        a1 = __hadd2(a1, i2h(__shfl_xor(h2i(a1), o)));
        a2 = __hadd2(a2, i2h(__shfl_xor(h2i(a2), o)));
        a3 = __hadd2(a3, i2h(__shfl_xor(h2i(a3), o)));
    }
    if (g == 0) {
        float inv = 1.f / (s_part + 1e-16f);
        float4 bA = b1v[2 * r], bB = b1v[2 * r + 1];
        float v[8] = {__low2float(a0), __high2float(a0), __low2float(a1), __high2float(a1),
                      __low2float(a2), __high2float(a2), __low2float(a3), __high2float(a3)};
        float vb[8] = {bA.x, bA.y, bA.z, bA.w, bB.x, bB.y, bB.z, bB.w};
        U16x8 o;
#pragma unroll
        for (int k = 0; k < 8; k += 2) {
            float u0 = fmaf(v[k], inv, vb[k]);
            float u1 = fmaf(v[k + 1], inv, vb[k + 1]);
            u0 = (u0 > 0.f) ? u0 : (__expf(u0) - 1.f);  // ELU
            u1 = (u1 > 0.f) ? u1 : (__expf(u1) - 1.f);
            o.h[k >> 1] = __floats2half2_rn(u0, u1);
        }
        *(uint4*)(hf + (size_t)wid * 128 + r * 8) = o.u;
    }
}

// ---------------- fused gather layer 2: packed-fp16 + 4-deep pipeline ----------
__global__ __launch_bounds__(256) void k_gather2(
    const int* __restrict__ cnt, const int* __restrict__ colell,
    const _Float16* __restrict__ h2, const float* __restrict__ alsrc,
    const float* __restrict__ aldst, const float4* __restrict__ b2v,
    float4* __restrict__ out4, int N) {
    int wid = (int)(((size_t)blockIdx.x * blockDim.x + threadIdx.x) >> 6);
    int lane = threadIdx.x & 63;
    if (wid >= N) return;
    int g = lane >> 4, r = lane & 15;
    int rc = (r < 10) ? r : 0;
    float ad = aldst[wid];
    float ls = lrelu(alsrc[wid] + ad);
    int nb = min(cnt[wid], 64);
    int sv = 0;
    float l = -1e30f;
    if (lane < nb) {
        sv = colell[(size_t)wid * 64 + lane];
        l = lrelu(alsrc[sv] + ad);
    }
    float m = l;
#pragma unroll
    for (int o = 32; o > 0; o >>= 1) m = fmaxf(m, __shfl_xor(m, o));
    m = fmaxf(m, ls);
    float e = (lane < nb) ? __expf(l - m) : 0.f;
    float es = (g == 0) ? __expf(ls - m) : 0.f;
    float s_part = es;
    __half2 esp = __floats2half2_rn(es, es);
    U16x4 hs;
    hs.u = *(const uint2*)(h2 + (size_t)wid * 40 + rc * 4);
    __half2 a0 = __hmul2(hs.h[0], esp), a1 = __hmul2(hs.h[1], esp);
    if (nb > 0) {
        int i0 = __shfl(sv, g);
        int i1 = __shfl(sv, 4 + g);
        int i2 = __shfl(sv, 8 + g);
        int i3 = __shfl(sv, 12 + g);
        float wA = __shfl(e, g), wB = __shfl(e, 4 + g);
        float wC = __shfl(e, 8 + g), wD = __shfl(e, 12 + g);
        U16x4 hA, hB, hC, hD;
        hA.u = *(const uint2*)(h2 + (size_t)i0 * 40 + rc * 4);
        hB.u = *(const uint2*)(h2 + (size_t)i1 * 40 + rc * 4);
        hC.u = *(const uint2*)(h2 + (size_t)i2 * 40 + rc * 4);
        hD.u = *(const uint2*)(h2 + (size_t)i3 * 40 + rc * 4);
        for (int j = 16; j < nb; j += 4) {
            int i4 = __shfl(sv, j + g);
            float wN = __shfl(e, j + g);
            U16x4 hN;
            hN.u = *(const uint2*)(h2 + (size_t)i4 * 40 + rc * 4);
            __half2 ww = __floats2half2_rn(wA, wA);
            s_part += wA;
            a0 = __hfma2(ww, hA.h[0], a0);
            a1 = __hfma2(ww, hA.h[1], a1);
            hA = hB; wA = wB;
            hB = hC; wB = wC;
            hC = hD; wC = wD;
            hD = hN; wD = wN;
        }
        {
            __half2 ww = __floats2half2_rn(wA, wA);
            s_part += wA;
            a0 = __hfma2(ww, hA.h[0], a0); a1 = __hfma2(ww, hA.h[1], a1);
        }
        {
            __half2 ww = __floats2half2_rn(wB, wB);
            s_part += wB;
            a0 = __hfma2(ww, hB.h[0], a0); a1 = __hfma2(ww, hB.h[1], a1);
        }
        {
            __half2 ww = __floats2half2_rn(wC, wC);
            s_part += wC;
            a0 = __hfma2(ww, hC.h[0], a0); a1 = __hfma2(ww, hC.h[1], a1);
        }
        {
            __half2 ww = __floats2half2_rn(wD, wD);
            s_part += wD;
            a0 = __hfma2(ww, hD.h[0], a0); a1 = __hfma2(ww, hD.h[1], a1);
        }
    }
#pragma unroll
    for (int o = 16; o < 64; o <<= 1) {
        s_part += __shfl_xor(s_part, o);
        a0 = __hadd2(a0, i2h(__shfl_xor(h2i(a0), o)));
        a1 = __hadd2(a1, i2h(__shfl_xor(h2i(a1), o)));
    }
    if (g == 0 && r < 10) {
        float inv = 1.f / (s_part + 1e-16f);
        float4 b = b2v[r];
        float4 o = make_float4(fmaf(__low2float(a0), inv, b.x),
                               fmaf(__high2float(a0), inv, b.y),
                               fmaf(__low2float(a1), inv, b.z),
                               fmaf(__high2float(a1), inv, b.w));
        out4[(size_t)wid * 10 + r] = o;
    }
}

extern "C" void kernel_launch(void* const* d_in, const int* in_sizes, int n_in,
                              void* d_out, int out_size, void* d_ws, size_t ws_size,
                              hipStream_t stream) {
    const float* x   = (const float*)d_in[0];
    const int*   ei  = (const int*)d_in[1];
    const float* W1  = (const float*)d_in[2];
    const float* as1 = (const float*)d_in[3];
    const float* ad1 = (const float*)d_in[4];
    const float* b1  = (const float*)d_in[5];
    const float* W2  = (const float*)d_in[6];
    const float* as2 = (const float*)d_in[7];
    const float* ad2 = (const float*)d_in[8];
    const float* b2  = (const float*)d_in[9];
    int N = in_sizes[0] / 128;
    int E = in_sizes[1] / 2;
    float4* out4 = (float4*)d_out;

    char* ws = (char*)d_ws;
    size_t off = 0;
    auto alloc = [&](size_t bytes) {
        char* p = ws + off;
        off += (bytes + 255) & ~(size_t)255;
        return p;
    };
    int*      cnt    = (int*)alloc((size_t)N * 4);       // zeroed in k_pack
    int*      colell = (int*)alloc((size_t)N * 64 * 4);  // ELL, stride 64
    _Float16* bp1    = (_Float16*)alloc(16384 * 2);
    _Float16* bp2    = (_Float16*)alloc(6144 * 2);
    _Float16* h1h    = (_Float16*)alloc((size_t)N * 128 * 2);  // fp16 [N][128]
    _Float16* hf     = (_Float16*)alloc((size_t)N * 128 * 2);  // fp16 [N][128]
    _Float16* h2h    = (_Float16*)alloc((size_t)N * 40 * 2);   // fp16 [N][40]
    float*    alsrc1 = (float*)alloc((size_t)N * 2 * 4);
    float*    aldst1 = (float*)alloc((size_t)N * 2 * 4);
    float*    alsrc2 = (float*)alloc((size_t)N * 4);
    float*    aldst2 = (float*)alloc((size_t)N * 4);

    dim3 b256(256);
    int ps = (N + 7) / 8;
    int gB = 8 * ((E + 255) / 256);
    int gP = (N > 22528 ? N + 255 : 22528 + 255) / 256;

    k_pack<<<gP, b256, 0, stream>>>(W1, W2, bp1, bp2, cnt, N);
    k_bucket<<<gB, b256, 0, stream>>>(ei, cnt, colell, E, ps);

    int gG = (N + 63) / 64;
    // layer 1
    k_gemm1<<<gG, b256, 0, stream>>>(x, bp1, as1, ad1, (__half2*)h1h, alsrc1, aldst1, N);
    k_gather1<<<(int)(((size_t)N * 64 + 255) / 256), b256, 0, stream>>>(
        cnt, colell, h1h, (const float2*)alsrc1, (const float2*)aldst1,
        (const float4*)b1, hf, N);

    // layer 2
    k_gemm2<<<gG, b256, 0, stream>>>(hf, bp2, as2, ad2, (__half2*)h2h, alsrc2, aldst2, N);
    k_gather2<<<(int)(((size_t)N * 64 + 255) / 256), b256, 0, stream>>>(
        cnt, colell, h2h, alsrc2, aldst2, (const float4*)b2, out4, N);
}

// Round 12
// 124.718 us; speedup vs baseline: 2.7896x; 1.0100x over previous
//
#include <hip/hip_runtime.h>
#include <hip/hip_fp16.h>

#define NEG_SLOPE 0.2f

typedef _Float16 f16x8 __attribute__((ext_vector_type(8)));
typedef float f32x4 __attribute__((ext_vector_type(4)));

__device__ __forceinline__ int h2i(__half2 h) { return *(int*)&h; }
__device__ __forceinline__ __half2 i2h(int i) { return *(__half2*)&i; }
__device__ __forceinline__ float lrelu(float v) { return (v > 0.f) ? v : NEG_SLOPE * v; }
__device__ __forceinline__ int pkmax(int a, int b) {
    int r;
    asm("v_pk_max_f16 %0, %1, %2" : "=v"(r) : "v"(a), "v"(b));
    return r;
}
__device__ __forceinline__ __half selh(int r, int packed) {
    return (r < 8) ? __low2half(i2h(packed)) : __high2half(i2h(packed));
}

union U16x8 { uint4 u; __half2 h[4]; };
union U16x4 { uint2 u; __half2 h[2]; };

// ---------------- pack W1/W2 into MFMA B-fragment order + zero cnt ----------
__global__ __launch_bounds__(256) void k_pack(const float* __restrict__ W1,
                                              const float* __restrict__ W2,
                                              _Float16* __restrict__ bp1,
                                              _Float16* __restrict__ bp2,
                                              int* __restrict__ cnt, int N) {
    int idx = blockIdx.x * 256 + threadIdx.x;
    if (idx < N) cnt[idx] = 0;
    if (idx < 16384) {  // W1: 4 ks * 8 nt * 64 * 8
        int j = idx & 7, l = (idx >> 3) & 63, nt = (idx >> 9) & 7, ks = idx >> 12;
        int k = ks * 32 + (l >> 4) * 8 + j;
        int col = nt * 16 + (l & 15);
        bp1[idx] = (_Float16)W1[k * 128 + col];
    }
    int idx2 = idx - 16384;
    if (idx2 >= 0 && idx2 < 6144) {  // W2: 4 ks * 3 nt * 64 * 8 (cols >=40 zero)
        int j = idx2 & 7, l = (idx2 >> 3) & 63, q = idx2 >> 9;
        int nt = q % 3, ks = q / 3;
        int k = ks * 32 + (l >> 4) * 8 + j;
        int col = nt * 16 + (l & 15);
        bp2[idx2] = (col < 40) ? (_Float16)W2[k * 40 + col] : (_Float16)0.f;
    }
}

// ---------------- one-pass ELL bucket build (2 edges/thread) ----------------
__global__ void k_bucket(const int* __restrict__ ei, int* __restrict__ cnt,
                         int* __restrict__ colell, int E, int ps) {
    int p = blockIdx.x & 7;
    int e = ((blockIdx.x >> 3) * blockDim.x + threadIdx.x) * 2;
    if (e >= E) return;
    int lo = p * ps, hi = lo + ps;
    int2 d2 = *(const int2*)(ei + E + e);
    if (d2.x >= lo && d2.x < hi) {
        int s = ei[e];
        int rank = atomicAdd(&cnt[d2.x], 1);
        if (rank < 64) colell[(size_t)d2.x * 64 + rank] = s;
    }
    if (e + 1 < E && d2.y >= lo && d2.y < hi) {
        int s = ei[e + 1];
        int rank = atomicAdd(&cnt[d2.y], 1);
        if (rank < 64) colell[(size_t)d2.y * 64 + rank] = s;
    }
}

// ---------------- GEMM1 (MFMA): h1 = x @ W1 + attention logits ----------------
__global__ __launch_bounds__(256) void k_gemm1(
    const float* __restrict__ x, const _Float16* __restrict__ bp1,
    const float* __restrict__ as1, const float* __restrict__ ad1,
    __half2* __restrict__ h1h, float* __restrict__ alsrc, float* __restrict__ aldst,
    int N) {
    int w = threadIdx.x >> 6, l = threadIdx.x & 63;
    int n0 = blockIdx.x * 64 + w * 16;
    int li = l & 15, lg = l >> 4;
    int arow = n0 + li;
    f16x8 a[4];
#pragma unroll
    for (int ks = 0; ks < 4; ks++) {
        float4 p0 = make_float4(0, 0, 0, 0), p1 = make_float4(0, 0, 0, 0);
        if (arow < N) {
            const float4* src = (const float4*)(x + (size_t)arow * 128 + ks * 32 + lg * 8);
            p0 = src[0];
            p1 = src[1];
        }
        f16x8 t;
        t[0] = (_Float16)p0.x; t[1] = (_Float16)p0.y; t[2] = (_Float16)p0.z; t[3] = (_Float16)p0.w;
        t[4] = (_Float16)p1.x; t[5] = (_Float16)p1.y; t[6] = (_Float16)p1.z; t[7] = (_Float16)p1.w;
        a[ks] = t;
    }
    f32x4 acc[8];
#pragma unroll
    for (int nt = 0; nt < 8; nt++) acc[nt] = (f32x4){0.f, 0.f, 0.f, 0.f};
    const f16x8* bp = (const f16x8*)bp1;
#pragma unroll
    for (int nt = 0; nt < 8; nt++)
#pragma unroll
        for (int ks = 0; ks < 4; ks++)
            acc[nt] = __builtin_amdgcn_mfma_f32_16x16x32_f16(a[ks], bp[(ks * 8 + nt) * 64 + l],
                                                             acc[nt], 0, 0, 0);
    float as1v[8], ad1v[8];
#pragma unroll
    for (int nt = 0; nt < 8; nt++) {
        as1v[nt] = as1[nt * 16 + li];
        ad1v[nt] = ad1[nt * 16 + li];
    }
#pragma unroll
    for (int r = 0; r < 4; r++) {
        float ps0 = 0, ps1 = 0, pd0 = 0, pd1 = 0;
#pragma unroll
        for (int nt = 0; nt < 4; nt++) {
            ps0 = fmaf(acc[nt][r], as1v[nt], ps0);
            pd0 = fmaf(acc[nt][r], ad1v[nt], pd0);
        }
#pragma unroll
        for (int nt = 4; nt < 8; nt++) {
            ps1 = fmaf(acc[nt][r], as1v[nt], ps1);
            pd1 = fmaf(acc[nt][r], ad1v[nt], pd1);
        }
#pragma unroll
        for (int o = 1; o < 16; o <<= 1) {
            ps0 += __shfl_xor(ps0, o);
            ps1 += __shfl_xor(ps1, o);
            pd0 += __shfl_xor(pd0, o);
            pd1 += __shfl_xor(pd1, o);
        }
        int node = n0 + lg * 4 + r;
        if (li == 0 && node < N) {
            alsrc[node * 2] = ps0;
            alsrc[node * 2 + 1] = ps1;
            aldst[node * 2] = pd0;
            aldst[node * 2 + 1] = pd1;
        }
    }
#pragma unroll
    for (int nt = 0; nt < 8; nt++)
#pragma unroll
        for (int r = 0; r < 4; r++) {
            float v = acc[nt][r];
            float p = __shfl_down(v, 1);
            int node = n0 + lg * 4 + r;
            if ((l & 1) == 0 && node < N)
                h1h[(size_t)node * 64 + nt * 8 + (li >> 1)] = __floats2half2_rn(v, p);
        }
}

// ---------------- fused gather layer 1 + GEMM2 ----------------
// Phase 1: per-wave node gather (packed fp16, 4-deep pipeline) -> ELU row in LDS.
// Phase 2: wave 0 computes h2 = hf @ W2 (MFMA, rows 0..3 = this block's nodes)
//          + layer-2 attention logits. Kills the standalone gemm2 kernel + hf buffer.
__global__ __launch_bounds__(256) void k_gather1(
    const int* __restrict__ cnt, const int* __restrict__ colell,
    const _Float16* __restrict__ h1, const float2* __restrict__ alsrc,
    const float2* __restrict__ aldst, const float4* __restrict__ b1v,
    const _Float16* __restrict__ bp2, const float* __restrict__ as2,
    const float* __restrict__ ad2, __half2* __restrict__ h2h,
    float* __restrict__ alsrc2, float* __restrict__ aldst2, int N) {
    __shared__ __align__(16) _Float16 hfl[4][128];
    int w = threadIdx.x >> 6;
    int lane = threadIdx.x & 63;
    int n0 = blockIdx.x * 4;
    int wid = n0 + w;
    if (wid < N) {
        int g = lane >> 4, r = lane & 15;
        float2 asn = alsrc[wid], ad = aldst[wid];
        float ls0 = lrelu(asn.x + ad.x);
        float ls1 = lrelu(asn.y + ad.y);
        int nb = min(cnt[wid], 64);
        int sv = 0;
        float l0 = -1e30f, l1 = -1e30f;
        if (lane < nb) {
            sv = colell[(size_t)wid * 64 + lane];
            float2 av = alsrc[sv];
            l0 = lrelu(av.x + ad.x);
            l1 = lrelu(av.y + ad.y);
        }
        int lpi = h2i(__floats2half2_rn(l0, l1));
#pragma unroll
        for (int o = 32; o > 0; o >>= 1) lpi = pkmax(lpi, __shfl_xor(lpi, o));
        __half2 lp = i2h(lpi);
        float m0 = fmaxf(__low2float(lp), ls0);
        float m1 = fmaxf(__high2float(lp), ls1);
        float e0 = (lane < nb) ? __expf(l0 - m0) : 0.f;
        float e1 = (lane < nb) ? __expf(l1 - m1) : 0.f;
        int we = h2i(__floats2half2_rn(e0, e1));
        float lsh = (r < 8) ? ls0 : ls1;
        float mh = (r < 8) ? m0 : m1;
        __half esh = __float2half((g == 0) ? __expf(lsh - mh) : 0.f);
        float s_part = __half2float(esh);
        __half2 esp = __half2half2(esh);
        U16x8 hs;
        hs.u = *(const uint4*)(h1 + (size_t)wid * 128 + r * 8);
        __half2 a0 = __hmul2(hs.h[0], esp), a1 = __hmul2(hs.h[1], esp),
                a2 = __hmul2(hs.h[2], esp), a3 = __hmul2(hs.h[3], esp);
        if (nb > 0) {
            int i0 = __shfl(sv, g),      p0 = __shfl(we, g);
            int i1 = __shfl(sv, 4 + g),  p1 = __shfl(we, 4 + g);
            int i2 = __shfl(sv, 8 + g),  p2 = __shfl(we, 8 + g);
            int i3 = __shfl(sv, 12 + g), p3 = __shfl(we, 12 + g);
            U16x8 hA, hB, hC, hD;
            hA.u = *(const uint4*)(h1 + (size_t)i0 * 128 + r * 8);
            hB.u = *(const uint4*)(h1 + (size_t)i1 * 128 + r * 8);
            hC.u = *(const uint4*)(h1 + (size_t)i2 * 128 + r * 8);
            hD.u = *(const uint4*)(h1 + (size_t)i3 * 128 + r * 8);
            __half wA = selh(r, p0), wB = selh(r, p1), wC = selh(r, p2), wD = selh(r, p3);
            for (int j = 16; j < nb; j += 4) {
                int i4 = __shfl(sv, j + g), p4 = __shfl(we, j + g);
                U16x8 hN;
                hN.u = *(const uint4*)(h1 + (size_t)i4 * 128 + r * 8);
                __half2 ww = __half2half2(wA);
                s_part += __half2float(wA);
                a0 = __hfma2(ww, hA.h[0], a0);
                a1 = __hfma2(ww, hA.h[1], a1);
                a2 = __hfma2(ww, hA.h[2], a2);
                a3 = __hfma2(ww, hA.h[3], a3);
                hA = hB; wA = wB;
                hB = hC; wB = wC;
                hC = hD; wC = wD;
                hD = hN; wD = selh(r, p4);
            }
            {
                __half2 ww = __half2half2(wA);
                s_part += __half2float(wA);
                a0 = __hfma2(ww, hA.h[0], a0); a1 = __hfma2(ww, hA.h[1], a1);
                a2 = __hfma2(ww, hA.h[2], a2); a3 = __hfma2(ww, hA.h[3], a3);
            }
            {
                __half2 ww = __half2half2(wB);
                s_part += __half2float(wB);
                a0 = __hfma2(ww, hB.h[0], a0); a1 = __hfma2(ww, hB.h[1], a1);
                a2 = __hfma2(ww, hB.h[2], a2); a3 = __hfma2(ww, hB.h[3], a3);
            }
            {
                __half2 ww = __half2half2(wC);
                s_part += __half2float(wC);
                a0 = __hfma2(ww, hC.h[0], a0); a1 = __hfma2(ww, hC.h[1], a1);
                a2 = __hfma2(ww, hC.h[2], a2); a3 = __hfma2(ww, hC.h[3], a3);
            }
            {
                __half2 ww = __half2half2(wD);
                s_part += __half2float(wD);
                a0 = __hfma2(ww, hD.h[0], a0); a1 = __hfma2(ww, hD.h[1], a1);
                a2 = __hfma2(ww, hD.h[2], a2); a3 = __hfma2(ww, hD.h[3], a3);
            }
        }
#pragma unroll
        for (int o = 16; o < 64; o <<= 1) {
            s_part += __shfl_xor(s_part, o);
            a0 = __hadd2(a0, i2h(__shfl_xor(h2i(a0), o)));
            a1 = __hadd2(a1, i2h(__shfl_xor(h2i(a1), o)));
            a2 = __hadd2(a2, i2h(__shfl_xor(h2i(a2), o)));
            a3 = __hadd2(a3, i2h(__shfl_xor(h2i(a3), o)));
        }
        if (g == 0) {
            float inv = 1.f / (s_part + 1e-16f);
            float4 bA = b1v[2 * r], bB = b1v[2 * r + 1];
            float v[8] = {__low2float(a0), __high2float(a0), __low2float(a1), __high2float(a1),
                          __low2float(a2), __high2float(a2), __low2float(a3), __high2float(a3)};
            float vb[8] = {bA.x, bA.y, bA.z, bA.w, bB.x, bB.y, bB.z, bB.w};
            U16x8 o;
#pragma unroll
            for (int k = 0; k < 8; k += 2) {
                float u0 = fmaf(v[k], inv, vb[k]);
                float u1 = fmaf(v[k + 1], inv, vb[k + 1]);
                u0 = (u0 > 0.f) ? u0 : (__expf(u0) - 1.f);  // ELU
                u1 = (u1 > 0.f) ? u1 : (__expf(u1) - 1.f);
                o.h[k >> 1] = __floats2half2_rn(u0, u1);
            }
            *(uint4*)(&hfl[w][r * 8]) = o.u;  // row to LDS (hf never hits global)
        }
    }
    __syncthreads();
    // ---- phase 2: gemm2 for this block's 4 nodes (wave 0 only) ----
    if (w == 0) {
        int li = lane & 15, lg = lane >> 4;
        f16x8 av[4];
        const f16x8* hrow = (const f16x8*)(&hfl[li & 3][0]);
#pragma unroll
        for (int ks = 0; ks < 4; ks++) {
            f16x8 t;
            if (li < 4) {
                t = hrow[ks * 4 + lg];
            } else {
#pragma unroll
                for (int k = 0; k < 8; k++) t[k] = (_Float16)0.f;
            }
            av[ks] = t;
        }
        f32x4 acc2[3];
#pragma unroll
        for (int nt = 0; nt < 3; nt++) acc2[nt] = (f32x4){0.f, 0.f, 0.f, 0.f};
        const f16x8* bp = (const f16x8*)bp2;
#pragma unroll
        for (int nt = 0; nt < 3; nt++)
#pragma unroll
            for (int ks = 0; ks < 4; ks++)
                acc2[nt] = __builtin_amdgcn_mfma_f32_16x16x32_f16(
                    av[ks], bp[(ks * 3 + nt) * 64 + lane], acc2[nt], 0, 0, 0);
        float as2v[3], ad2v[3];
#pragma unroll
        for (int nt = 0; nt < 3; nt++) {
            int col = nt * 16 + li;
            as2v[nt] = (col < 40) ? as2[col] : 0.f;
            ad2v[nt] = (col < 40) ? ad2[col] : 0.f;
        }
#pragma unroll
        for (int r = 0; r < 4; r++) {
            float ps = 0, pd = 0;
#pragma unroll
            for (int nt = 0; nt < 3; nt++) {
                ps = fmaf(acc2[nt][r], as2v[nt], ps);
                pd = fmaf(acc2[nt][r], ad2v[nt], pd);
            }
#pragma unroll
            for (int o = 1; o < 16; o <<= 1) {
                ps += __shfl_xor(ps, o);
                pd += __shfl_xor(pd, o);
            }
            int node = n0 + r;
            if (li == 0 && lg == 0 && node < N) {
                alsrc2[node] = ps;
                aldst2[node] = pd;
            }
        }
#pragma unroll
        for (int nt = 0; nt < 3; nt++)
#pragma unroll
            for (int r = 0; r < 4; r++) {
                float v = acc2[nt][r];
                float p = __shfl_down(v, 1);
                int node = n0 + r;
                int col = nt * 16 + li;
                if (lg == 0 && (lane & 1) == 0 && col < 40 && node < N)
                    h2h[(size_t)node * 20 + nt * 8 + (li >> 1)] = __floats2half2_rn(v, p);
            }
    }
}

// ---------------- fused gather layer 2: packed-fp16 + 4-deep pipeline ----------
__global__ __launch_bounds__(256) void k_gather2(
    const int* __restrict__ cnt, const int* __restrict__ colell,
    const _Float16* __restrict__ h2, const float* __restrict__ alsrc,
    const float* __restrict__ aldst, const float4* __restrict__ b2v,
    float4* __restrict__ out4, int N) {
    int wid = (int)(((size_t)blockIdx.x * blockDim.x + threadIdx.x) >> 6);
    int lane = threadIdx.x & 63;
    if (wid >= N) return;
    int g = lane >> 4, r = lane & 15;
    int rc = (r < 10) ? r : 0;
    float ad = aldst[wid];
    float ls = lrelu(alsrc[wid] + ad);
    int nb = min(cnt[wid], 64);
    int sv = 0;
    float l = -1e30f;
    if (lane < nb) {
        sv = colell[(size_t)wid * 64 + lane];
        l = lrelu(alsrc[sv] + ad);
    }
    float m = l;
#pragma unroll
    for (int o = 32; o > 0; o >>= 1) m = fmaxf(m, __shfl_xor(m, o));
    m = fmaxf(m, ls);
    float e = (lane < nb) ? __expf(l - m) : 0.f;
    float es = (g == 0) ? __expf(ls - m) : 0.f;
    float s_part = es;
    __half2 esp = __floats2half2_rn(es, es);
    U16x4 hs;
    hs.u = *(const uint2*)(h2 + (size_t)wid * 40 + rc * 4);
    __half2 a0 = __hmul2(hs.h[0], esp), a1 = __hmul2(hs.h[1], esp);
    if (nb > 0) {
        int i0 = __shfl(sv, g);
        int i1 = __shfl(sv, 4 + g);
        int i2 = __shfl(sv, 8 + g);
        int i3 = __shfl(sv, 12 + g);
        float wA = __shfl(e, g), wB = __shfl(e, 4 + g);
        float wC = __shfl(e, 8 + g), wD = __shfl(e, 12 + g);
        U16x4 hA, hB, hC, hD;
        hA.u = *(const uint2*)(h2 + (size_t)i0 * 40 + rc * 4);
        hB.u = *(const uint2*)(h2 + (size_t)i1 * 40 + rc * 4);
        hC.u = *(const uint2*)(h2 + (size_t)i2 * 40 + rc * 4);
        hD.u = *(const uint2*)(h2 + (size_t)i3 * 40 + rc * 4);
        for (int j = 16; j < nb; j += 4) {
            int i4 = __shfl(sv, j + g);
            float wN = __shfl(e, j + g);
            U16x4 hN;
            hN.u = *(const uint2*)(h2 + (size_t)i4 * 40 + rc * 4);
            __half2 ww = __floats2half2_rn(wA, wA);
            s_part += wA;
            a0 = __hfma2(ww, hA.h[0], a0);
            a1 = __hfma2(ww, hA.h[1], a1);
            hA = hB; wA = wB;
            hB = hC; wB = wC;
            hC = hD; wC = wD;
            hD = hN; wD = wN;
        }
        {
            __half2 ww = __floats2half2_rn(wA, wA);
            s_part += wA;
            a0 = __hfma2(ww, hA.h[0], a0); a1 = __hfma2(ww, hA.h[1], a1);
        }
        {
            __half2 ww = __floats2half2_rn(wB, wB);
            s_part += wB;
            a0 = __hfma2(ww, hB.h[0], a0); a1 = __hfma2(ww, hB.h[1], a1);
        }
        {
            __half2 ww = __floats2half2_rn(wC, wC);
            s_part += wC;
            a0 = __hfma2(ww, hC.h[0], a0); a1 = __hfma2(ww, hC.h[1], a1);
        }
        {
            __half2 ww = __floats2half2_rn(wD, wD);
            s_part += wD;
            a0 = __hfma2(ww, hD.h[0], a0); a1 = __hfma2(ww, hD.h[1], a1);
        }
    }
#pragma unroll
    for (int o = 16; o < 64; o <<= 1) {
        s_part += __shfl_xor(s_part, o);
        a0 = __hadd2(a0, i2h(__shfl_xor(h2i(a0), o)));
        a1 = __hadd2(a1, i2h(__shfl_xor(h2i(a1), o)));
    }
    if (g == 0 && r < 10) {
        float inv = 1.f / (s_part + 1e-16f);
        float4 b = b2v[r];
        float4 o = make_float4(fmaf(__low2float(a0), inv, b.x),
                               fmaf(__high2float(a0), inv, b.y),
                               fmaf(__low2float(a1), inv, b.z),
                               fmaf(__high2float(a1), inv, b.w));
        out4[(size_t)wid * 10 + r] = o;
    }
}

extern "C" void kernel_launch(void* const* d_in, const int* in_sizes, int n_in,
                              void* d_out, int out_size, void* d_ws, size_t ws_size,
                              hipStream_t stream) {
    const float* x   = (const float*)d_in[0];
    const int*   ei  = (const int*)d_in[1];
    const float* W1  = (const float*)d_in[2];
    const float* as1 = (const float*)d_in[3];
    const float* ad1 = (const float*)d_in[4];
    const float* b1  = (const float*)d_in[5];
    const float* W2  = (const float*)d_in[6];
    const float* as2 = (const float*)d_in[7];
    const float* ad2 = (const float*)d_in[8];
    const float* b2  = (const float*)d_in[9];
    int N = in_sizes[0] / 128;
    int E = in_sizes[1] / 2;
    float4* out4 = (float4*)d_out;

    char* ws = (char*)d_ws;
    size_t off = 0;
    auto alloc = [&](size_t bytes) {
        char* p = ws + off;
        off += (bytes + 255) & ~(size_t)255;
        return p;
    };
    int*      cnt    = (int*)alloc((size_t)N * 4);       // zeroed in k_pack
    int*      colell = (int*)alloc((size_t)N * 64 * 4);  // ELL, stride 64
    _Float16* bp1    = (_Float16*)alloc(16384 * 2);
    _Float16* bp2    = (_Float16*)alloc(6144 * 2);
    _Float16* h1h    = (_Float16*)alloc((size_t)N * 128 * 2);  // fp16 [N][128]
    _Float16* h2h    = (_Float16*)alloc((size_t)N * 40 * 2);   // fp16 [N][40]
    float*    alsrc1 = (float*)alloc((size_t)N * 2 * 4);
    float*    aldst1 = (float*)alloc((size_t)N * 2 * 4);
    float*    alsrc2 = (float*)alloc((size_t)N * 4);
    float*    aldst2 = (float*)alloc((size_t)N * 4);

    dim3 b256(256);
    int ps = (N + 7) / 8;
    int gB = 8 * ((E + 511) / 512);
    int gP = (N > 22528 ? N + 255 : 22528 + 255) / 256;

    k_pack<<<gP, b256, 0, stream>>>(W1, W2, bp1, bp2, cnt, N);
    k_bucket<<<gB, b256, 0, stream>>>(ei, cnt, colell, E, ps);

    int gG = (N + 63) / 64;
    k_gemm1<<<gG, b256, 0, stream>>>(x, bp1, as1, ad1, (__half2*)h1h, alsrc1, aldst1, N);
    // gather1 + fused gemm2 (4 nodes per block)
    k_gather1<<<(N + 3) / 4, b256, 0, stream>>>(
        cnt, colell, h1h, (const float2*)alsrc1, (const float2*)aldst1,
        (const float4*)b1, bp2, as2, ad2, (__half2*)h2h, alsrc2, aldst2, N);
    k_gather2<<<(int)(((size_t)N * 64 + 255) / 256), b256, 0, stream>>>(
        cnt, colell, h2h, alsrc2, aldst2, (const float4*)b2, out4, N);
}